// Round 1
// baseline (804.244 us; speedup 1.0000x reference)
//
#include <hip/hip_runtime.h>
#include <hip/hip_bf16.h>

using bf16 = __hip_bfloat16;
using bf16x8 = __attribute__((ext_vector_type(8))) short;
using f32x4  = __attribute__((ext_vector_type(4))) float;

#define MFMA16(a,b,c) __builtin_amdgcn_mfma_f32_16x16x32_bf16(a,b,c,0,0,0)

static __device__ __forceinline__ unsigned short f2bs(float v){
  bf16 t = __float2bfloat16(v); unsigned short s; __builtin_memcpy(&s,&t,2); return s;
}
static __device__ __forceinline__ float bs2f(unsigned short s){
  bf16 t; __builtin_memcpy(&t,&s,2); return __bfloat162float(t);
}

// ---------------- merged weight splits: fp32 -> bf16 hi (+ optional lo) ----------------
struct SplitArgs {
  const float* src[7];
  unsigned short* hi[7];
  unsigned short* lo[7];
  int n[7];
};

__global__ __launch_bounds__(256) void k_splitall(SplitArgs a){
  int j = blockIdx.y;
  int n = a.n[j];
  long e = ((long)blockIdx.x*256 + threadIdx.x)*4;
  if (e >= n) return;
  const float* src = a.src[j];
  unsigned short* hi = a.hi[j];
  unsigned short* lo = a.lo[j];
  unsigned short h[4], l[4];
  #pragma unroll
  for (int t=0;t<4;++t){
    float v = src[e+t];
    h[t] = f2bs(v);
    l[t] = f2bs(v - bs2f(h[t]));
  }
  uint2 vh; __builtin_memcpy(&vh,h,8);
  *(uint2*)(hi + e) = vh;
  if (lo){ uint2 vl; __builtin_memcpy(&vl,l,8); *(uint2*)(lo + e) = vl; }
}

// ---------------- merged pad: (nmat,49,512) fp32 -> (nmat,64,512) split bf16 ----------------
// blocks [0,6144): class_feature (192 mats); [6144,6656): global_feature (16 mats).
// block 0 also zeroes the 288-float stats buffer.
__global__ __launch_bounds__(256) void k_pad2(const float* __restrict__ cf, const float* __restrict__ gf,
                                              unsigned short* __restrict__ cfh, unsigned short* __restrict__ cfl,
                                              unsigned short* __restrict__ gfh, unsigned short* __restrict__ gfl,
                                              float* __restrict__ stats){
  int blk = blockIdx.x;
  if (blk == 0){
    stats[threadIdx.x] = 0.f;
    if (threadIdx.x < 32) stats[256 + threadIdx.x] = 0.f;
  }
  const float* src; unsigned short* dh; unsigned short* dl; long base;
  if (blk < 6144){ src = cf; dh = cfh; dl = cfl; base = (long)blk*1024; }
  else           { src = gf; dh = gfh; dl = gfl; base = (long)(blk-6144)*1024; }
  long e = base + (long)threadIdx.x*4;
  int rem = (int)(e % (64*512));
  int d = rem >> 9;
  unsigned short h[4], l[4];
  if (d < 49){
    int mat = (int)(e / (64*512));
    int c = rem & 511;
    const float* s = src + ((long)mat*49 + d)*512 + c;
    #pragma unroll
    for (int t=0;t<4;++t){
      float v = s[t];
      h[t] = f2bs(v);
      l[t] = f2bs(v - bs2f(h[t]));
    }
  } else {
    #pragma unroll
    for (int t=0;t<4;++t){ h[t]=0; l[t]=0; }
  }
  uint2 vh, vl; __builtin_memcpy(&vh,h,8); __builtin_memcpy(&vl,l,8);
  *(uint2*)(dh + e) = vh;
  *(uint2*)(dl + e) = vl;
}

// ---------------- C = A @ W^T + bias. Split-bf16 inputs, fp32 acc. ----------------
// TERMS: 3 = Ah*Wh + Al*Wh + Ah*Wl ; 2 = Ah*W + Al*W ; 1 = Ah*Wh.
// BIAS: 0 none, 1 per-col fp32, 2 per-row fp32. SOUT: write split (hi+lo) or single bf16.
template<int TERMS, int BIAS, bool SOUT, int WM, int WN>
__global__ __launch_bounds__(256) void k_gemm(
    const unsigned short* __restrict__ Ah, const unsigned short* __restrict__ Al, long a_bs,
    const unsigned short* __restrict__ Wh, const unsigned short* __restrict__ Wl, long w_bs,
    const float* __restrict__ bias,
    unsigned short* __restrict__ Ch, unsigned short* __restrict__ Cl, long c_bs,
    int K, int N)
{
  const int z = blockIdx.z;
  const unsigned short* Abh = Ah + (long)z*a_bs;
  const unsigned short* Abl = (TERMS>=2) ? Al + (long)z*a_bs : nullptr;
  const unsigned short* Wbh = Wh + (long)z*w_bs;
  const unsigned short* Wbl = (TERMS==3) ? Wl + (long)z*w_bs : nullptr;
  unsigned short* Cbh = Ch + (long)z*c_bs;
  unsigned short* Cbl = SOUT ? Cl + (long)z*c_bs : nullptr;
  int tid = threadIdx.x, wave = tid>>6, lane = tid&63, quad = lane>>4, l15 = lane&15;
  int wm = (WN==1) ? wave : wave / WN;
  int wn = (WN==1) ? 0    : wave % WN;
  int row0 = blockIdx.x*(64*WM) + wm*64;
  int col0 = blockIdx.y*(64*WN) + wn*64;
  f32x4 acc[4][4] = {};
  for (int k0 = 0; k0 < K; k0 += 32) {
    int ka = k0 + quad*8;
    bf16x8 ah[4], al[4], wh[4], wl[4];
    #pragma unroll
    for (int t=0;t<4;++t){
      ah[t] = *(const bf16x8*)(Abh + (long)(row0 + t*16 + l15)*K + ka);
      if (TERMS>=2) al[t] = *(const bf16x8*)(Abl + (long)(row0 + t*16 + l15)*K + ka);
      wh[t] = *(const bf16x8*)(Wbh + (long)(col0 + t*16 + l15)*K + ka);
      if (TERMS==3) wl[t] = *(const bf16x8*)(Wbl + (long)(col0 + t*16 + l15)*K + ka);
    }
    #pragma unroll
    for (int tm=0;tm<4;++tm){
      #pragma unroll
      for (int tn=0;tn<4;++tn){
        acc[tm][tn] = MFMA16(ah[tm], wh[tn], acc[tm][tn]);
        if (TERMS>=2) acc[tm][tn] = MFMA16(al[tm], wh[tn], acc[tm][tn]);
        if (TERMS==3) acc[tm][tn] = MFMA16(ah[tm], wl[tn], acc[tm][tn]);
      }
    }
  }
  #pragma unroll
  for (int tm=0;tm<4;++tm){
    #pragma unroll
    for (int tn=0;tn<4;++tn){
      #pragma unroll
      for (int r=0;r<4;++r){
        int row = row0 + tm*16 + quad*4 + r;
        int col = col0 + tn*16 + l15;
        float v = acc[tm][tn][r];
        if (BIAS==1) v += bias[col];
        else if (BIAS==2) v += bias[row];
        long idx = (long)row*N + col;
        unsigned short h = f2bs(v);
        Cbh[idx] = h;
        if (SOUT) Cbl[idx] = f2bs(v - bs2f(h));
      }
    }
  }
}

// ---------------- stage-1 attention (split precision throughout) ----------------
__global__ __launch_bounds__(256) void k_attn1(
    const unsigned short* __restrict__ qh, const unsigned short* __restrict__ ql,
    const unsigned short* __restrict__ kh, const unsigned short* __restrict__ kl,
    const unsigned short* __restrict__ vh, const unsigned short* __restrict__ vl,
    unsigned short* __restrict__ fh, unsigned short* __restrict__ fl)
{
  __shared__ float Sb[64][72];
  __shared__ __align__(16) unsigned short Ph[64][72];
  __shared__ __align__(16) unsigned short Pl[64][72];
  int bn = blockIdx.x, b = bn/12;
  int tid=threadIdx.x, wave=tid>>6, lane=tid&63, quad=lane>>4, l15=lane&15;
  const unsigned short* Qh = qh + (long)bn*64*256;
  const unsigned short* Ql = ql + (long)bn*64*256;
  const unsigned short* Kh = kh + (long)b *64*256;
  const unsigned short* Kl = kl + (long)b *64*256;
  f32x4 sacc[4] = {};
  for (int k0=0;k0<256;k0+=32){
    int ka = k0 + quad*8;
    bf16x8 qfh = *(const bf16x8*)(Qh + (long)(16*wave + l15)*256 + ka);
    bf16x8 qfl = *(const bf16x8*)(Ql + (long)(16*wave + l15)*256 + ka);
    #pragma unroll
    for (int t=0;t<4;++t){
      bf16x8 kfh = *(const bf16x8*)(Kh + (long)(t*16 + l15)*256 + ka);
      bf16x8 kfl = *(const bf16x8*)(Kl + (long)(t*16 + l15)*256 + ka);
      sacc[t] = MFMA16(qfh, kfh, sacc[t]);
      sacc[t] = MFMA16(qfl, kfh, sacc[t]);
      sacc[t] = MFMA16(qfh, kfl, sacc[t]);
    }
  }
  #pragma unroll
  for (int t=0;t<4;++t)
    #pragma unroll
    for (int r=0;r<4;++r)
      Sb[16*wave + quad*4 + r][t*16 + l15] = sacc[t][r] * 0.0625f;
  __syncthreads();
  if (tid < 64){
    float m = -1e30f;
    for (int c=0;c<49;++c) m = fmaxf(m, Sb[tid][c]);
    float s = 0.f;
    for (int c=0;c<49;++c){ float e = __expf(Sb[tid][c]-m); s += e; Sb[tid][c]=e; }
    float inv = 1.f/s;
    for (int c=0;c<64;++c){
      float p = (c<49) ? Sb[tid][c]*inv : 0.f;
      unsigned short h = f2bs(p);
      Ph[tid][c] = h;
      Pl[tid][c] = f2bs(p - bs2f(h));
    }
  }
  __syncthreads();
  const unsigned short* Vh = vh + (long)b*512*64;
  const unsigned short* Vl = vl + (long)b*512*64;
  unsigned short* Fh = fh + (long)bn*64*512;
  unsigned short* Fl = fl + (long)bn*64*512;
  for (int nc=0;nc<4;++nc){
    f32x4 acc[8] = {};
    #pragma unroll
    for (int kk=0;kk<2;++kk){
      int k0 = kk*32 + quad*8;
      bf16x8 pfh = *(const bf16x8*)(&Ph[16*wave + l15][k0]);
      bf16x8 pfl = *(const bf16x8*)(&Pl[16*wave + l15][k0]);
      #pragma unroll
      for (int t=0;t<8;++t){
        bf16x8 vfh = *(const bf16x8*)(Vh + (long)(nc*128 + t*16 + l15)*64 + k0);
        bf16x8 vfl = *(const bf16x8*)(Vl + (long)(nc*128 + t*16 + l15)*64 + k0);
        acc[t] = MFMA16(pfh, vfh, acc[t]);
        acc[t] = MFMA16(pfl, vfh, acc[t]);
        acc[t] = MFMA16(pfh, vfl, acc[t]);
      }
    }
    #pragma unroll
    for (int t=0;t<8;++t){
      #pragma unroll
      for (int r=0;r<4;++r){
        long idx = (long)(16*wave + quad*4 + r)*512 + nc*128 + t*16 + l15;
        float v = acc[t][r];
        unsigned short h = f2bs(v);
        Fh[idx] = h;
        Fl[idx] = f2bs(v - bs2f(h));
      }
    }
  }
}

// ---------------- stage-2 logits + softmax -> P2 (single bf16) ----------------
__global__ __launch_bounds__(256) void k_attnA(
    const unsigned short* __restrict__ qh, const unsigned short* __restrict__ ql,
    const unsigned short* __restrict__ kh, const unsigned short* __restrict__ kl,
    unsigned short* __restrict__ P2)
{
  __shared__ float Sb[64][72];
  int p = blockIdx.x, b = blockIdx.y;
  int i = p/12, j = p%12;
  int tid=threadIdx.x, wave=tid>>6, lane=tid&63, quad=lane>>4, l15=lane&15;
  const unsigned short* Qh = qh + ((long)(b*12 + j))*64*256;
  const unsigned short* Ql = ql + ((long)(b*12 + j))*64*256;
  const unsigned short* Kh = kh + ((long)(b*12 + i))*64*256;
  const unsigned short* Kl = kl + ((long)(b*12 + i))*64*256;
  f32x4 sacc[4] = {};
  for (int k0=0;k0<256;k0+=32){
    int ka = k0 + quad*8;
    bf16x8 qfh = *(const bf16x8*)(Qh + (long)(16*wave + l15)*256 + ka);
    bf16x8 qfl = *(const bf16x8*)(Ql + (long)(16*wave + l15)*256 + ka);
    #pragma unroll
    for (int t=0;t<4;++t){
      bf16x8 kfh = *(const bf16x8*)(Kh + (long)(t*16 + l15)*256 + ka);
      bf16x8 kfl = *(const bf16x8*)(Kl + (long)(t*16 + l15)*256 + ka);
      sacc[t] = MFMA16(qfh, kfh, sacc[t]);
      sacc[t] = MFMA16(qfl, kfh, sacc[t]);
      sacc[t] = MFMA16(qfh, kfl, sacc[t]);
    }
  }
  #pragma unroll
  for (int t=0;t<4;++t)
    #pragma unroll
    for (int r=0;r<4;++r)
      Sb[16*wave + quad*4 + r][t*16 + l15] = sacc[t][r] * 0.0625f;
  __syncthreads();
  if (tid < 64){
    float m = -1e30f;
    for (int c=0;c<49;++c) m = fmaxf(m, Sb[tid][c]);
    float s = 0.f;
    for (int c=0;c<49;++c){ float e = __expf(Sb[tid][c]-m); s += e; Sb[tid][c]=e; }
    float inv = 1.f/s;
    unsigned short* row = P2 + ((long)(b*144 + p)*64 + tid)*64;
    for (int c=0;c<64;++c)
      row[c] = f2bs((c<49) ? Sb[tid][c]*inv : 0.f);
  }
}

// ---------------- stage-2 PV pass 1: BN stats only (no out write) ----------------
__global__ __launch_bounds__(256) void k_attnS(
    const unsigned short* __restrict__ P2, const unsigned short* __restrict__ EV,
    float* __restrict__ stats)
{
  __shared__ float red[8];
  int p = blockIdx.x, b = blockIdx.y;
  int i = p/12;
  int tid=threadIdx.x, wave=tid>>6, lane=tid&63, quad=lane>>4, l15=lane&15;
  const unsigned short* Pz = P2 + (long)(b*144 + p)*64*64;
  const unsigned short* E  = EV + ((long)(b*12 + i))*512*64;
  float psum = 0.f, psq = 0.f;
  for (int nc=0;nc<4;++nc){
    f32x4 acc[8] = {};
    #pragma unroll
    for (int kk=0;kk<2;++kk){
      int k0 = kk*32 + quad*8;
      bf16x8 pf = *(const bf16x8*)(Pz + (long)(16*wave + l15)*64 + k0);
      #pragma unroll
      for (int t=0;t<8;++t){
        bf16x8 ef = *(const bf16x8*)(E + (long)(nc*128 + t*16 + l15)*64 + k0);
        acc[t] = MFMA16(pf, ef, acc[t]);
      }
    }
    #pragma unroll
    for (int t=0;t<8;++t){
      #pragma unroll
      for (int r=0;r<4;++r){
        int q = 16*wave + quad*4 + r;
        if (q < 49){
          float v = acc[t][r];
          psum += v; psq += v*v;
        }
      }
    }
  }
  #pragma unroll
  for (int off=32; off; off>>=1){
    psum += __shfl_xor(psum, off, 64);
    psq  += __shfl_xor(psq , off, 64);
  }
  if (lane==0){ red[wave]=psum; red[4+wave]=psq; }
  __syncthreads();
  if (tid==0){
    atomicAdd(&stats[p],     red[0]+red[1]+red[2]+red[3]);
    atomicAdd(&stats[144+p], red[4]+red[5]+red[6]+red[7]);
  }
}

// ---------------- stage-2 PV pass 2: recompute, normalize, write fp32 out ----------------
__global__ __launch_bounds__(256) void k_attnW(
    const unsigned short* __restrict__ P2, const unsigned short* __restrict__ EV,
    const float* __restrict__ stats,
    const float* __restrict__ bnw, const float* __restrict__ bnb,
    float* __restrict__ out)
{
  int p = blockIdx.x, b = blockIdx.y;
  int i = p/12;
  int tid=threadIdx.x, wave=tid>>6, lane=tid&63, quad=lane>>4, l15=lane&15;
  const unsigned short* Pz = P2 + (long)(b*144 + p)*64*64;
  const unsigned short* E  = EV + ((long)(b*12 + i))*512*64;
  const float invc = 1.f/401408.f;
  float mean = stats[p] * invc;
  float var  = stats[144+p] * invc - mean*mean;
  float g  = bnw[p] * rsqrtf(var + 1e-5f);
  float sh = bnb[p] - mean*g;
  for (int nc=0;nc<4;++nc){
    f32x4 acc[8] = {};
    #pragma unroll
    for (int kk=0;kk<2;++kk){
      int k0 = kk*32 + quad*8;
      bf16x8 pf = *(const bf16x8*)(Pz + (long)(16*wave + l15)*64 + k0);
      #pragma unroll
      for (int t=0;t<8;++t){
        bf16x8 ef = *(const bf16x8*)(E + (long)(nc*128 + t*16 + l15)*64 + k0);
        acc[t] = MFMA16(pf, ef, acc[t]);
      }
    }
    #pragma unroll
    for (int t=0;t<8;++t){
      #pragma unroll
      for (int r=0;r<4;++r){
        int q = 16*wave + quad*4 + r;
        if (q < 49)
          out[(((long)(b*144 + p))*49 + q)*512 + (nc*128 + t*16 + l15)] = acc[t][r]*g + sh;
      }
    }
  }
}

extern "C" void kernel_launch(void* const* d_in, const int* in_sizes, int n_in,
                              void* d_out, int out_size, void* d_ws, size_t ws_size,
                              hipStream_t stream)
{
  const float* cf  = (const float*)d_in[0];
  const float* gf  = (const float*)d_in[1];
  const float* fqw = (const float*)d_in[2];   const float* fqb = (const float*)d_in[3];
  const float* fkw = (const float*)d_in[4];   const float* fkb = (const float*)d_in[5];
  const float* fvw = (const float*)d_in[6];   const float* fvb = (const float*)d_in[7];
  const float* aqw = (const float*)d_in[8];   const float* aqb = (const float*)d_in[9];
  const float* akw = (const float*)d_in[10];  const float* akb = (const float*)d_in[11];
  const float* avw = (const float*)d_in[12];  const float* avb = (const float*)d_in[13];
  const float* ew  = (const float*)d_in[14];  const float* ebv = (const float*)d_in[15];
  const float* bnw = (const float*)d_in[16];  const float* bnb = (const float*)d_in[17];

  // ---- d_ws (~31.5 MB): stats | P2 (weights overlaid; dead before P2 written) | EV ----
  char* WS = (char*)d_ws;
  float* stats = (float*)WS;                                   // 288 fp32
  unsigned short* P2 = (unsigned short*)(WS + 4096);           // 16*144*64*64
  unsigned short* EV = (unsigned short*)(WS + 4096 + 18874368);// 192*512*64
  unsigned short* wp = P2;  // weights overlay (consumed before attnA writes P2)
  unsigned short* w_fqw_h = wp; wp += 131072;  unsigned short* w_fqw_l = wp; wp += 131072;
  unsigned short* w_fkw_h = wp; wp += 131072;  unsigned short* w_fkw_l = wp; wp += 131072;
  unsigned short* w_fvw_h = wp; wp += 262144;  unsigned short* w_fvw_l = wp; wp += 262144;
  unsigned short* w_aqw_h = wp; wp += 131072;  unsigned short* w_aqw_l = wp; wp += 131072;
  unsigned short* w_akw_h = wp; wp += 131072;  unsigned short* w_akw_l = wp; wp += 131072;
  unsigned short* w_avw_h = wp; wp += 262144;
  unsigned short* w_ew_h  = wp; wp += 262144;

  // ---- d_out (231 MB fp32) as bf16 scratch for intermediates dead before k_attnW ----
  unsigned short* S = (unsigned short*)d_out;
  unsigned short* cfh = S; S += 6291456;  unsigned short* cfl = S; S += 6291456;
  unsigned short* gfh = S; S += 524288;   unsigned short* gfl = S; S += 524288;
  unsigned short* q1h = S; S += 3145728;  unsigned short* q1l = S; S += 3145728;
  unsigned short* k1h = S; S += 262144;   unsigned short* k1l = S; S += 262144;
  unsigned short* v1h = S; S += 524288;   unsigned short* v1l = S; S += 524288;
  unsigned short* feh = S; S += 6291456;  unsigned short* fel = S; S += 6291456;
  unsigned short* q2h = S; S += 3145728;  unsigned short* q2l = S; S += 3145728;
  unsigned short* k2h = S; S += 3145728;  unsigned short* k2l = S; S += 3145728;
  unsigned short* v2  = S; S += 6291456;  // single bf16

  // pad both inputs + zero stats (1 launch)
  k_pad2<<<6656, 256, 0, stream>>>(cf, gf, cfh, cfl, gfh, gfl, stats);

  // all 7 weight splits (1 launch)
  SplitArgs sa;
  sa.src[0]=fqw; sa.hi[0]=w_fqw_h; sa.lo[0]=w_fqw_l; sa.n[0]=131072;
  sa.src[1]=fkw; sa.hi[1]=w_fkw_h; sa.lo[1]=w_fkw_l; sa.n[1]=131072;
  sa.src[2]=fvw; sa.hi[2]=w_fvw_h; sa.lo[2]=w_fvw_l; sa.n[2]=262144;
  sa.src[3]=aqw; sa.hi[3]=w_aqw_h; sa.lo[3]=w_aqw_l; sa.n[3]=131072;
  sa.src[4]=akw; sa.hi[4]=w_akw_h; sa.lo[4]=w_akw_l; sa.n[4]=131072;
  sa.src[5]=avw; sa.hi[5]=w_avw_h; sa.lo[5]=nullptr; sa.n[5]=262144;
  sa.src[6]=ew;  sa.hi[6]=w_ew_h;  sa.lo[6]=nullptr; sa.n[6]=262144;
  k_splitall<<<dim3(256,7), 256, 0, stream>>>(sa);

  // q1 = cfp @ fqw^T + fqb   (12288,256) split out
  k_gemm<3,1,true,1,4><<<dim3(192,1,1),256,0,stream>>>(cfh,cfl,0, w_fqw_h,w_fqw_l,0, fqb, q1h,q1l,0, 512,256);
  // k1 = gfp @ fkw^T + fkb   (1024,256)
  k_gemm<3,1,true,1,4><<<dim3(16,1,1),256,0,stream>>>(gfh,gfl,0, w_fkw_h,w_fkw_l,0, fkb, k1h,k1l,0, 512,256);
  // v1T[b] = fvw @ gfp[b]^T + fvb(row)   (16 x 512,64)
  k_gemm<3,2,true,4,1><<<dim3(2,1,16),256,0,stream>>>(w_fvw_h,w_fvw_l,0, gfh,gfl,(long)64*512, fvb, v1h,v1l,(long)512*64, 512,64);

  k_attn1<<<192,256,0,stream>>>(q1h,q1l,k1h,k1l,v1h,v1l,feh,fel);

  // Q2/K2 = fea @ a{q,k}w^T + b  (12288,256) split out
  k_gemm<3,1,true,1,4><<<dim3(192,1,1),256,0,stream>>>(feh,fel,0, w_aqw_h,w_aqw_l,0, aqb, q2h,q2l,0, 512,256);
  k_gemm<3,1,true,1,4><<<dim3(192,1,1),256,0,stream>>>(feh,fel,0, w_akw_h,w_akw_l,0, akb, k2h,k2l,0, 512,256);
  // V2 = fea @ avw^T + avb  (12288,512) single out, 2-term
  k_gemm<2,1,false,1,4><<<dim3(192,2,1),256,0,stream>>>(feh,fel,0, w_avw_h,nullptr,0, avb, v2,nullptr,0, 512,512);
  // EV[bn] = ew @ V2[bn]^T + edge_b(row)  (192 x 512,64) single
  k_gemm<1,2,false,4,1><<<dim3(2,1,192),256,0,stream>>>(w_ew_h,nullptr,0, v2,nullptr,(long)64*512, ebv, EV,nullptr,(long)512*64, 512,64);

  k_attnA<<<dim3(144,16),256,0,stream>>>(q2h,q2l,k2h,k2l,P2);
  // pass 1: stats only; pass 2: recompute PV, fused BN normalize, write fp32 out
  k_attnS<<<dim3(144,16),256,0,stream>>>(P2,EV,stats);
  k_attnW<<<dim3(144,16),256,0,stream>>>(P2,EV,stats,bnw,bnb,(float*)d_out);
}

// Round 2
// 790.917 us; speedup vs baseline: 1.0168x; 1.0168x over previous
//
#include <hip/hip_runtime.h>
#include <hip/hip_bf16.h>

using bf16 = __hip_bfloat16;
using bf16x8 = __attribute__((ext_vector_type(8))) short;
using f32x4  = __attribute__((ext_vector_type(4))) float;

#define MFMA16(a,b,c) __builtin_amdgcn_mfma_f32_16x16x32_bf16(a,b,c,0,0,0)

static __device__ __forceinline__ unsigned short f2bs(float v){
  bf16 t = __float2bfloat16(v); unsigned short s; __builtin_memcpy(&s,&t,2); return s;
}
static __device__ __forceinline__ float bs2f(unsigned short s){
  bf16 t; __builtin_memcpy(&t,&s,2); return __bfloat162float(t);
}

// ---------------- merged weight splits: fp32 -> bf16 hi (+ optional lo) ----------------
struct SplitArgs {
  const float* src[7];
  unsigned short* hi[7];
  unsigned short* lo[7];
  int n[7];
};

__global__ __launch_bounds__(256) void k_splitall(SplitArgs a){
  int j = blockIdx.y;
  int n = a.n[j];
  long e = ((long)blockIdx.x*256 + threadIdx.x)*4;
  if (e >= n) return;
  const float* src = a.src[j];
  unsigned short* hi = a.hi[j];
  unsigned short* lo = a.lo[j];
  unsigned short h[4], l[4];
  #pragma unroll
  for (int t=0;t<4;++t){
    float v = src[e+t];
    h[t] = f2bs(v);
    l[t] = f2bs(v - bs2f(h[t]));
  }
  uint2 vh; __builtin_memcpy(&vh,h,8);
  *(uint2*)(hi + e) = vh;
  if (lo){ uint2 vl; __builtin_memcpy(&vl,l,8); *(uint2*)(lo + e) = vl; }
}

// ---------------- merged pad: (nmat,49,512) fp32 -> (nmat,64,512) split bf16 ----------------
// blocks [0,6144): class_feature (192 mats); [6144,6656): global_feature (16 mats).
// block 0 also zeroes the 288-float stats buffer.
__global__ __launch_bounds__(256) void k_pad2(const float* __restrict__ cf, const float* __restrict__ gf,
                                              unsigned short* __restrict__ cfh, unsigned short* __restrict__ cfl,
                                              unsigned short* __restrict__ gfh, unsigned short* __restrict__ gfl,
                                              float* __restrict__ stats){
  int blk = blockIdx.x;
  if (blk == 0){
    stats[threadIdx.x] = 0.f;
    if (threadIdx.x < 32) stats[256 + threadIdx.x] = 0.f;
  }
  const float* src; unsigned short* dh; unsigned short* dl; long base;
  if (blk < 6144){ src = cf; dh = cfh; dl = cfl; base = (long)blk*1024; }
  else           { src = gf; dh = gfh; dl = gfl; base = (long)(blk-6144)*1024; }
  long e = base + (long)threadIdx.x*4;
  int rem = (int)(e % (64*512));
  int d = rem >> 9;
  unsigned short h[4], l[4];
  if (d < 49){
    int mat = (int)(e / (64*512));
    int c = rem & 511;
    const float* s = src + ((long)mat*49 + d)*512 + c;
    #pragma unroll
    for (int t=0;t<4;++t){
      float v = s[t];
      h[t] = f2bs(v);
      l[t] = f2bs(v - bs2f(h[t]));
    }
  } else {
    #pragma unroll
    for (int t=0;t<4;++t){ h[t]=0; l[t]=0; }
  }
  uint2 vh, vl; __builtin_memcpy(&vh,h,8); __builtin_memcpy(&vl,l,8);
  *(uint2*)(dh + e) = vh;
  *(uint2*)(dl + e) = vl;
}

// ---------------- C = A @ W^T + bias. Split-bf16 inputs, fp32 acc. ----------------
template<int TERMS, int BIAS, bool SOUT, int WM, int WN>
__global__ __launch_bounds__(256) void k_gemm(
    const unsigned short* __restrict__ Ah, const unsigned short* __restrict__ Al, long a_bs,
    const unsigned short* __restrict__ Wh, const unsigned short* __restrict__ Wl, long w_bs,
    const float* __restrict__ bias,
    unsigned short* __restrict__ Ch, unsigned short* __restrict__ Cl, long c_bs,
    int K, int N)
{
  const int z = blockIdx.z;
  const unsigned short* Abh = Ah + (long)z*a_bs;
  const unsigned short* Abl = (TERMS>=2) ? Al + (long)z*a_bs : nullptr;
  const unsigned short* Wbh = Wh + (long)z*w_bs;
  const unsigned short* Wbl = (TERMS==3) ? Wl + (long)z*w_bs : nullptr;
  unsigned short* Cbh = Ch + (long)z*c_bs;
  unsigned short* Cbl = SOUT ? Cl + (long)z*c_bs : nullptr;
  int tid = threadIdx.x, wave = tid>>6, lane = tid&63, quad = lane>>4, l15 = lane&15;
  int wm = (WN==1) ? wave : wave / WN;
  int wn = (WN==1) ? 0    : wave % WN;
  int row0 = blockIdx.x*(64*WM) + wm*64;
  int col0 = blockIdx.y*(64*WN) + wn*64;
  f32x4 acc[4][4] = {};
  for (int k0 = 0; k0 < K; k0 += 32) {
    int ka = k0 + quad*8;
    bf16x8 ah[4], al[4], wh[4], wl[4];
    #pragma unroll
    for (int t=0;t<4;++t){
      ah[t] = *(const bf16x8*)(Abh + (long)(row0 + t*16 + l15)*K + ka);
      if (TERMS>=2) al[t] = *(const bf16x8*)(Abl + (long)(row0 + t*16 + l15)*K + ka);
      wh[t] = *(const bf16x8*)(Wbh + (long)(col0 + t*16 + l15)*K + ka);
      if (TERMS==3) wl[t] = *(const bf16x8*)(Wbl + (long)(col0 + t*16 + l15)*K + ka);
    }
    #pragma unroll
    for (int tm=0;tm<4;++tm){
      #pragma unroll
      for (int tn=0;tn<4;++tn){
        acc[tm][tn] = MFMA16(ah[tm], wh[tn], acc[tm][tn]);
        if (TERMS>=2) acc[tm][tn] = MFMA16(al[tm], wh[tn], acc[tm][tn]);
        if (TERMS==3) acc[tm][tn] = MFMA16(ah[tm], wl[tn], acc[tm][tn]);
      }
    }
  }
  #pragma unroll
  for (int tm=0;tm<4;++tm){
    #pragma unroll
    for (int tn=0;tn<4;++tn){
      #pragma unroll
      for (int r=0;r<4;++r){
        int row = row0 + tm*16 + quad*4 + r;
        int col = col0 + tn*16 + l15;
        float v = acc[tm][tn][r];
        if (BIAS==1) v += bias[col];
        else if (BIAS==2) v += bias[row];
        long idx = (long)row*N + col;
        unsigned short h = f2bs(v);
        Cbh[idx] = h;
        if (SOUT) Cbl[idx] = f2bs(v - bs2f(h));
      }
    }
  }
}

// ---------------- stage-1 attention (split precision throughout) ----------------
__global__ __launch_bounds__(256) void k_attn1(
    const unsigned short* __restrict__ qh, const unsigned short* __restrict__ ql,
    const unsigned short* __restrict__ kh, const unsigned short* __restrict__ kl,
    const unsigned short* __restrict__ vh, const unsigned short* __restrict__ vl,
    unsigned short* __restrict__ fh, unsigned short* __restrict__ fl)
{
  __shared__ float Sb[64][72];
  __shared__ __align__(16) unsigned short Ph[64][72];
  __shared__ __align__(16) unsigned short Pl[64][72];
  int bn = blockIdx.x, b = bn/12;
  int tid=threadIdx.x, wave=tid>>6, lane=tid&63, quad=lane>>4, l15=lane&15;
  const unsigned short* Qh = qh + (long)bn*64*256;
  const unsigned short* Ql = ql + (long)bn*64*256;
  const unsigned short* Kh = kh + (long)b *64*256;
  const unsigned short* Kl = kl + (long)b *64*256;
  f32x4 sacc[4] = {};
  for (int k0=0;k0<256;k0+=32){
    int ka = k0 + quad*8;
    bf16x8 qfh = *(const bf16x8*)(Qh + (long)(16*wave + l15)*256 + ka);
    bf16x8 qfl = *(const bf16x8*)(Ql + (long)(16*wave + l15)*256 + ka);
    #pragma unroll
    for (int t=0;t<4;++t){
      bf16x8 kfh = *(const bf16x8*)(Kh + (long)(t*16 + l15)*256 + ka);
      bf16x8 kfl = *(const bf16x8*)(Kl + (long)(t*16 + l15)*256 + ka);
      sacc[t] = MFMA16(qfh, kfh, sacc[t]);
      sacc[t] = MFMA16(qfl, kfh, sacc[t]);
      sacc[t] = MFMA16(qfh, kfl, sacc[t]);
    }
  }
  #pragma unroll
  for (int t=0;t<4;++t)
    #pragma unroll
    for (int r=0;r<4;++r)
      Sb[16*wave + quad*4 + r][t*16 + l15] = sacc[t][r] * 0.0625f;
  __syncthreads();
  if (tid < 64){
    float m = -1e30f;
    for (int c=0;c<49;++c) m = fmaxf(m, Sb[tid][c]);
    float s = 0.f;
    for (int c=0;c<49;++c){ float e = __expf(Sb[tid][c]-m); s += e; Sb[tid][c]=e; }
    float inv = 1.f/s;
    for (int c=0;c<64;++c){
      float p = (c<49) ? Sb[tid][c]*inv : 0.f;
      unsigned short h = f2bs(p);
      Ph[tid][c] = h;
      Pl[tid][c] = f2bs(p - bs2f(h));
    }
  }
  __syncthreads();
  const unsigned short* Vh = vh + (long)b*512*64;
  const unsigned short* Vl = vl + (long)b*512*64;
  unsigned short* Fh = fh + (long)bn*64*512;
  unsigned short* Fl = fl + (long)bn*64*512;
  for (int nc=0;nc<4;++nc){
    f32x4 acc[8] = {};
    #pragma unroll
    for (int kk=0;kk<2;++kk){
      int k0 = kk*32 + quad*8;
      bf16x8 pfh = *(const bf16x8*)(&Ph[16*wave + l15][k0]);
      bf16x8 pfl = *(const bf16x8*)(&Pl[16*wave + l15][k0]);
      #pragma unroll
      for (int t=0;t<8;++t){
        bf16x8 vfh = *(const bf16x8*)(Vh + (long)(nc*128 + t*16 + l15)*64 + k0);
        bf16x8 vfl = *(const bf16x8*)(Vl + (long)(nc*128 + t*16 + l15)*64 + k0);
        acc[t] = MFMA16(pfh, vfh, acc[t]);
        acc[t] = MFMA16(pfl, vfh, acc[t]);
        acc[t] = MFMA16(pfh, vfl, acc[t]);
      }
    }
    #pragma unroll
    for (int t=0;t<8;++t){
      #pragma unroll
      for (int r=0;r<4;++r){
        long idx = (long)(16*wave + quad*4 + r)*512 + nc*128 + t*16 + l15;
        float v = acc[t][r];
        unsigned short h = f2bs(v);
        Fh[idx] = h;
        Fl[idx] = f2bs(v - bs2f(h));
      }
    }
  }
}

// ---------------- Gram: G[b,i] = EV^T EV (64x64 fp32), evec[b,i][k] = sum_c EV[c,k] ----------------
__global__ __launch_bounds__(256) void k_gram(
    const unsigned short* __restrict__ EV,
    float* __restrict__ G, float* __restrict__ evec)
{
  __shared__ __align__(16) unsigned short Et[64][520];
  __shared__ float ered[4][64];
  int bn = blockIdx.x;
  int tid = threadIdx.x, wave = tid>>6, lane = tid&63, quad = lane>>4, l15 = lane&15;
  const unsigned short* E = EV + (long)bn*512*64;
  // stage EV^T into LDS: Et[k][c] = EV[c][k]
  for (int rep=0; rep<16; ++rep){
    int idx = rep*256 + tid;          // 0..4095
    int c = idx >> 3;                 // 0..511
    int kg = idx & 7;                 // 0..7
    bf16x8 v = *(const bf16x8*)(E + (long)c*64 + kg*8);
    #pragma unroll
    for (int j=0;j<8;++j) Et[kg*8+j][c] = (unsigned short)v[j];
  }
  __syncthreads();
  // G = Et · Et^T ; wave handles m-strip [wave*16, wave*16+16)
  f32x4 acc[4] = {};
  for (int ks=0; ks<16; ++ks){
    bf16x8 a = *(const bf16x8*)(&Et[wave*16 + l15][ks*32 + quad*8]);
    #pragma unroll
    for (int n=0;n<4;++n){
      bf16x8 bb = *(const bf16x8*)(&Et[n*16 + l15][ks*32 + quad*8]);
      acc[n] = MFMA16(a, bb, acc[n]);
    }
  }
  float* Gb = G + (long)bn*4096;
  #pragma unroll
  for (int n=0;n<4;++n)
    #pragma unroll
    for (int r=0;r<4;++r)
      Gb[(wave*16 + quad*4 + r)*64 + n*16 + l15] = acc[n][r];
  // evec
  int k = tid & 63, part = tid >> 6;
  float s = 0.f;
  for (int c = part*128; c < part*128 + 128; ++c) s += bs2f(Et[k][c]);
  ered[part][k] = s;
  __syncthreads();
  if (tid < 64) evec[(long)bn*64 + tid] = ered[0][tid] + ered[1][tid] + ered[2][tid] + ered[3][tid];
}

// ---------------- stage-2 logits + softmax -> P2, fused BN-stats via Gram trick ----------------
// psum = sum_k (colsum P)_k * evec_k ; psq = <P^T P, G>   (P rows q>=49 and cols k>=49 zeroed)
__global__ __launch_bounds__(256) void k_attnA(
    const unsigned short* __restrict__ qh, const unsigned short* __restrict__ ql,
    const unsigned short* __restrict__ kh, const unsigned short* __restrict__ kl,
    unsigned short* __restrict__ P2,
    const float* __restrict__ G, const float* __restrict__ evec,
    float* __restrict__ stats)
{
  __shared__ float Sb[64][72];
  __shared__ __align__(16) unsigned short Pt[64][72];
  __shared__ float red[8];
  int p = blockIdx.x, b = blockIdx.y;
  int i = p/12, j = p%12;
  int tid=threadIdx.x, wave=tid>>6, lane=tid&63, quad=lane>>4, l15=lane&15;
  const unsigned short* Qh = qh + ((long)(b*12 + j))*64*256;
  const unsigned short* Ql = ql + ((long)(b*12 + j))*64*256;
  const unsigned short* Kh = kh + ((long)(b*12 + i))*64*256;
  const unsigned short* Kl = kl + ((long)(b*12 + i))*64*256;
  f32x4 sacc[4] = {};
  for (int k0=0;k0<256;k0+=32){
    int ka = k0 + quad*8;
    bf16x8 qfh = *(const bf16x8*)(Qh + (long)(16*wave + l15)*256 + ka);
    bf16x8 qfl = *(const bf16x8*)(Ql + (long)(16*wave + l15)*256 + ka);
    #pragma unroll
    for (int t=0;t<4;++t){
      bf16x8 kfh = *(const bf16x8*)(Kh + (long)(t*16 + l15)*256 + ka);
      bf16x8 kfl = *(const bf16x8*)(Kl + (long)(t*16 + l15)*256 + ka);
      sacc[t] = MFMA16(qfh, kfh, sacc[t]);
      sacc[t] = MFMA16(qfl, kfh, sacc[t]);
      sacc[t] = MFMA16(qfh, kfl, sacc[t]);
    }
  }
  #pragma unroll
  for (int t=0;t<4;++t)
    #pragma unroll
    for (int r=0;r<4;++r)
      Sb[16*wave + quad*4 + r][t*16 + l15] = sacc[t][r] * 0.0625f;
  __syncthreads();
  if (tid < 64){
    float m = -1e30f;
    for (int c=0;c<49;++c) m = fmaxf(m, Sb[tid][c]);
    float s = 0.f;
    for (int c=0;c<49;++c){ float e = __expf(Sb[tid][c]-m); s += e; Sb[tid][c]=e; }
    float inv = 1.f/s;
    unsigned short* row = P2 + ((long)(b*144 + p)*64 + tid)*64;
    for (int c=0;c<64;++c){
      float pv = (tid < 49 && c < 49) ? Sb[tid][c]*inv : 0.f;
      unsigned short h = f2bs(pv);
      row[c] = h;
      Pt[c][tid] = h;   // transpose: Pt[k][q]
    }
  }
  __syncthreads();
  // P^T P (64x64x64) and dot with G
  const float* Gb = G + (long)(b*12 + i)*4096;
  f32x4 pac[4] = {};
  #pragma unroll
  for (int ks=0; ks<2; ++ks){
    bf16x8 a = *(const bf16x8*)(&Pt[wave*16 + l15][ks*32 + quad*8]);
    #pragma unroll
    for (int n=0;n<4;++n){
      bf16x8 bb = *(const bf16x8*)(&Pt[n*16 + l15][ks*32 + quad*8]);
      pac[n] = MFMA16(a, bb, pac[n]);
    }
  }
  float psq = 0.f;
  #pragma unroll
  for (int n=0;n<4;++n)
    #pragma unroll
    for (int r=0;r<4;++r)
      psq += pac[n][r] * Gb[(wave*16 + quad*4 + r)*64 + n*16 + l15];
  #pragma unroll
  for (int off=32; off; off>>=1) psq += __shfl_xor(psq, off, 64);
  if (lane==0) red[4+wave] = psq;
  // psum (wave 0): s_k = colsum of P = rowsum of Pt
  float psm = 0.f;
  if (tid < 64){
    float s = 0.f;
    for (int q=0;q<64;++q) s += bs2f(Pt[tid][q]);
    psm = s * evec[(long)(b*12 + i)*64 + tid];
    #pragma unroll
    for (int off=32; off; off>>=1) psm += __shfl_xor(psm, off, 64);
  }
  __syncthreads();
  if (tid == 0){
    atomicAdd(&stats[p],     psm);
    atomicAdd(&stats[144+p], red[4]+red[5]+red[6]+red[7]);
  }
}

// ---------------- stage-2 PV: recompute, normalize, write fp32 out ----------------
__global__ __launch_bounds__(256) void k_attnW(
    const unsigned short* __restrict__ P2, const unsigned short* __restrict__ EV,
    const float* __restrict__ stats,
    const float* __restrict__ bnw, const float* __restrict__ bnb,
    float* __restrict__ out)
{
  int p = blockIdx.x, b = blockIdx.y;
  int i = p/12;
  int tid=threadIdx.x, wave=tid>>6, lane=tid&63, quad=lane>>4, l15=lane&15;
  const unsigned short* Pz = P2 + (long)(b*144 + p)*64*64;
  const unsigned short* E  = EV + ((long)(b*12 + i))*512*64;
  const float invc = 1.f/401408.f;
  float mean = stats[p] * invc;
  float var  = stats[144+p] * invc - mean*mean;
  float g  = bnw[p] * rsqrtf(var + 1e-5f);
  float sh = bnb[p] - mean*g;
  for (int nc=0;nc<4;++nc){
    f32x4 acc[8] = {};
    #pragma unroll
    for (int kk=0;kk<2;++kk){
      int k0 = kk*32 + quad*8;
      bf16x8 pf = *(const bf16x8*)(Pz + (long)(16*wave + l15)*64 + k0);
      #pragma unroll
      for (int t=0;t<8;++t){
        bf16x8 ef = *(const bf16x8*)(E + (long)(nc*128 + t*16 + l15)*64 + k0);
        acc[t] = MFMA16(pf, ef, acc[t]);
      }
    }
    #pragma unroll
    for (int t=0;t<8;++t){
      #pragma unroll
      for (int r=0;r<4;++r){
        int q = 16*wave + quad*4 + r;
        if (q < 49)
          out[(((long)(b*144 + p))*49 + q)*512 + (nc*128 + t*16 + l15)] = acc[t][r]*g + sh;
      }
    }
  }
}

extern "C" void kernel_launch(void* const* d_in, const int* in_sizes, int n_in,
                              void* d_out, int out_size, void* d_ws, size_t ws_size,
                              hipStream_t stream)
{
  const float* cf  = (const float*)d_in[0];
  const float* gf  = (const float*)d_in[1];
  const float* fqw = (const float*)d_in[2];   const float* fqb = (const float*)d_in[3];
  const float* fkw = (const float*)d_in[4];   const float* fkb = (const float*)d_in[5];
  const float* fvw = (const float*)d_in[6];   const float* fvb = (const float*)d_in[7];
  const float* aqw = (const float*)d_in[8];   const float* aqb = (const float*)d_in[9];
  const float* akw = (const float*)d_in[10];  const float* akb = (const float*)d_in[11];
  const float* avw = (const float*)d_in[12];  const float* avb = (const float*)d_in[13];
  const float* ew  = (const float*)d_in[14];  const float* ebv = (const float*)d_in[15];
  const float* bnw = (const float*)d_in[16];  const float* bnb = (const float*)d_in[17];

  // ---- d_ws (~31.5 MB): stats | P2 (weights overlaid; dead before P2 written) | EV ----
  char* WS = (char*)d_ws;
  float* stats = (float*)WS;                                   // 288 fp32
  unsigned short* P2 = (unsigned short*)(WS + 4096);           // 16*144*64*64
  unsigned short* EV = (unsigned short*)(WS + 4096 + 18874368);// 192*512*64
  unsigned short* wp = P2;  // weights overlay (consumed before attnA writes P2)
  unsigned short* w_fqw_h = wp; wp += 131072;  unsigned short* w_fqw_l = wp; wp += 131072;
  unsigned short* w_fkw_h = wp; wp += 131072;  unsigned short* w_fkw_l = wp; wp += 131072;
  unsigned short* w_fvw_h = wp; wp += 262144;  unsigned short* w_fvw_l = wp; wp += 262144;
  unsigned short* w_aqw_h = wp; wp += 131072;  unsigned short* w_aqw_l = wp; wp += 131072;
  unsigned short* w_akw_h = wp; wp += 131072;  unsigned short* w_akw_l = wp; wp += 131072;
  unsigned short* w_avw_h = wp; wp += 262144;
  unsigned short* w_ew_h  = wp; wp += 262144;

  // ---- d_out (231 MB fp32) as bf16 scratch for intermediates dead before k_attnW ----
  unsigned short* S = (unsigned short*)d_out;
  unsigned short* cfh = S; S += 6291456;  unsigned short* cfl = S; S += 6291456;
  unsigned short* gfh = S; S += 524288;   unsigned short* gfl = S; S += 524288;
  unsigned short* q1h = S; S += 3145728;  unsigned short* q1l = S; S += 3145728;
  unsigned short* k1h = S; S += 262144;   unsigned short* k1l = S; S += 262144;
  unsigned short* v1h = S; S += 524288;   unsigned short* v1l = S; S += 524288;
  unsigned short* feh = S; S += 6291456;  unsigned short* fel = S; S += 6291456;
  unsigned short* q2h = S; S += 3145728;  unsigned short* q2l = S; S += 3145728;
  unsigned short* k2h = S; S += 3145728;  unsigned short* k2l = S; S += 3145728;
  unsigned short* v2  = S; S += 6291456;  // single bf16
  float* G    = (float*)S; S += 1572864;  // 192 * 64*64 fp32 Gram matrices
  float* evec = (float*)S; S += 24576;    // 192 * 64 fp32 column sums

  // pad both inputs + zero stats (1 launch)
  k_pad2<<<6656, 256, 0, stream>>>(cf, gf, cfh, cfl, gfh, gfl, stats);

  // all 7 weight splits (1 launch)
  SplitArgs sa;
  sa.src[0]=fqw; sa.hi[0]=w_fqw_h; sa.lo[0]=w_fqw_l; sa.n[0]=131072;
  sa.src[1]=fkw; sa.hi[1]=w_fkw_h; sa.lo[1]=w_fkw_l; sa.n[1]=131072;
  sa.src[2]=fvw; sa.hi[2]=w_fvw_h; sa.lo[2]=w_fvw_l; sa.n[2]=262144;
  sa.src[3]=aqw; sa.hi[3]=w_aqw_h; sa.lo[3]=w_aqw_l; sa.n[3]=131072;
  sa.src[4]=akw; sa.hi[4]=w_akw_h; sa.lo[4]=w_akw_l; sa.n[4]=131072;
  sa.src[5]=avw; sa.hi[5]=w_avw_h; sa.lo[5]=nullptr; sa.n[5]=262144;
  sa.src[6]=ew;  sa.hi[6]=w_ew_h;  sa.lo[6]=nullptr; sa.n[6]=262144;
  k_splitall<<<dim3(256,7), 256, 0, stream>>>(sa);

  // q1 = cfp @ fqw^T + fqb   (12288,256) split out
  k_gemm<3,1,true,1,4><<<dim3(192,1,1),256,0,stream>>>(cfh,cfl,0, w_fqw_h,w_fqw_l,0, fqb, q1h,q1l,0, 512,256);
  // k1 = gfp @ fkw^T + fkb   (1024,256)
  k_gemm<3,1,true,1,4><<<dim3(16,1,1),256,0,stream>>>(gfh,gfl,0, w_fkw_h,w_fkw_l,0, fkb, k1h,k1l,0, 512,256);
  // v1T[b] = fvw @ gfp[b]^T + fvb(row)   (16 x 512,64)
  k_gemm<3,2,true,4,1><<<dim3(2,1,16),256,0,stream>>>(w_fvw_h,w_fvw_l,0, gfh,gfl,(long)64*512, fvb, v1h,v1l,(long)512*64, 512,64);

  k_attn1<<<192,256,0,stream>>>(q1h,q1l,k1h,k1l,v1h,v1l,feh,fel);

  // Q2/K2 = fea @ a{q,k}w^T + b  (12288,256) split out
  k_gemm<3,1,true,1,4><<<dim3(192,1,1),256,0,stream>>>(feh,fel,0, w_aqw_h,w_aqw_l,0, aqb, q2h,q2l,0, 512,256);
  k_gemm<3,1,true,1,4><<<dim3(192,1,1),256,0,stream>>>(feh,fel,0, w_akw_h,w_akw_l,0, akb, k2h,k2l,0, 512,256);
  // V2 = fea @ avw^T + avb  (12288,512) single out, 2-term
  k_gemm<2,1,false,1,4><<<dim3(192,2,1),256,0,stream>>>(feh,fel,0, w_avw_h,nullptr,0, avb, v2,nullptr,0, 512,512);
  // EV[bn] = ew @ V2[bn]^T + edge_b(row)  (192 x 512,64) single
  k_gemm<1,2,false,4,1><<<dim3(2,1,192),256,0,stream>>>(w_ew_h,nullptr,0, v2,nullptr,(long)64*512, ebv, EV,nullptr,(long)512*64, 512,64);

  // Gram matrices of EV (replaces the full stats PV pass)
  k_gram<<<192,256,0,stream>>>(EV, G, evec);

  // softmax + P2 + fused BN stats
  k_attnA<<<dim3(144,16),256,0,stream>>>(q2h,q2l,k2h,k2l,P2,G,evec,stats);

  // PV + fused BN normalize, write fp32 out
  k_attnW<<<dim3(144,16),256,0,stream>>>(P2,EV,stats,bnw,bnb,(float*)d_out);
}

// Round 3
// 746.932 us; speedup vs baseline: 1.0767x; 1.0589x over previous
//
#include <hip/hip_runtime.h>
#include <hip/hip_bf16.h>

using bf16 = __hip_bfloat16;
using bf16x8 = __attribute__((ext_vector_type(8))) short;
using f32x4  = __attribute__((ext_vector_type(4))) float;

#define MFMA16(a,b,c) __builtin_amdgcn_mfma_f32_16x16x32_bf16(a,b,c,0,0,0)

static __device__ __forceinline__ unsigned short f2bs(float v){
  bf16 t = __float2bfloat16(v); unsigned short s; __builtin_memcpy(&s,&t,2); return s;
}
static __device__ __forceinline__ float bs2f(unsigned short s){
  bf16 t; __builtin_memcpy(&t,&s,2); return __bfloat162float(t);
}

// ---------------- merged weight splits: fp32 -> bf16 hi (+ optional lo) ----------------
struct SplitArgs {
  const float* src[7];
  unsigned short* hi[7];
  unsigned short* lo[7];
  int n[7];
};

__global__ __launch_bounds__(256) void k_splitall(SplitArgs a){
  int j = blockIdx.y;
  int n = a.n[j];
  long e = ((long)blockIdx.x*256 + threadIdx.x)*4;
  if (e >= n) return;
  const float* src = a.src[j];
  unsigned short* hi = a.hi[j];
  unsigned short* lo = a.lo[j];
  unsigned short h[4], l[4];
  #pragma unroll
  for (int t=0;t<4;++t){
    float v = src[e+t];
    h[t] = f2bs(v);
    l[t] = f2bs(v - bs2f(h[t]));
  }
  uint2 vh; __builtin_memcpy(&vh,h,8);
  *(uint2*)(hi + e) = vh;
  if (lo){ uint2 vl; __builtin_memcpy(&vl,l,8); *(uint2*)(lo + e) = vl; }
}

// ---------------- merged pad: (nmat,49,512) fp32 -> (nmat,64,512) split bf16 ----------------
__global__ __launch_bounds__(256) void k_pad2(const float* __restrict__ cf, const float* __restrict__ gf,
                                              unsigned short* __restrict__ cfh, unsigned short* __restrict__ cfl,
                                              unsigned short* __restrict__ gfh, unsigned short* __restrict__ gfl,
                                              float* __restrict__ stats){
  int blk = blockIdx.x;
  if (blk == 0){
    stats[threadIdx.x] = 0.f;
    if (threadIdx.x < 32) stats[256 + threadIdx.x] = 0.f;
  }
  const float* src; unsigned short* dh; unsigned short* dl; long base;
  if (blk < 6144){ src = cf; dh = cfh; dl = cfl; base = (long)blk*1024; }
  else           { src = gf; dh = gfh; dl = gfl; base = (long)(blk-6144)*1024; }
  long e = base + (long)threadIdx.x*4;
  int rem = (int)(e % (64*512));
  int d = rem >> 9;
  unsigned short h[4], l[4];
  if (d < 49){
    int mat = (int)(e / (64*512));
    int c = rem & 511;
    const float* s = src + ((long)mat*49 + d)*512 + c;
    #pragma unroll
    for (int t=0;t<4;++t){
      float v = s[t];
      h[t] = f2bs(v);
      l[t] = f2bs(v - bs2f(h[t]));
    }
  } else {
    #pragma unroll
    for (int t=0;t<4;++t){ h[t]=0; l[t]=0; }
  }
  uint2 vh, vl; __builtin_memcpy(&vh,h,8); __builtin_memcpy(&vl,l,8);
  *(uint2*)(dh + e) = vh;
  *(uint2*)(dl + e) = vl;
}

// ---------------- C = A @ W^T + bias. Split-bf16 inputs, fp32 acc. ----------------
template<int TERMS, int BIAS, bool SOUT, int WM, int WN>
__global__ __launch_bounds__(256) void k_gemm(
    const unsigned short* __restrict__ Ah, const unsigned short* __restrict__ Al, long a_bs,
    const unsigned short* __restrict__ Wh, const unsigned short* __restrict__ Wl, long w_bs,
    const float* __restrict__ bias,
    unsigned short* __restrict__ Ch, unsigned short* __restrict__ Cl, long c_bs,
    int K, int N)
{
  const int z = blockIdx.z;
  const unsigned short* Abh = Ah + (long)z*a_bs;
  const unsigned short* Abl = (TERMS>=2) ? Al + (long)z*a_bs : nullptr;
  const unsigned short* Wbh = Wh + (long)z*w_bs;
  const unsigned short* Wbl = (TERMS==3) ? Wl + (long)z*w_bs : nullptr;
  unsigned short* Cbh = Ch + (long)z*c_bs;
  unsigned short* Cbl = SOUT ? Cl + (long)z*c_bs : nullptr;
  int tid = threadIdx.x, wave = tid>>6, lane = tid&63, quad = lane>>4, l15 = lane&15;
  int wm = (WN==1) ? wave : wave / WN;
  int wn = (WN==1) ? 0    : wave % WN;
  int row0 = blockIdx.x*(64*WM) + wm*64;
  int col0 = blockIdx.y*(64*WN) + wn*64;
  f32x4 acc[4][4] = {};
  #pragma unroll 2
  for (int k0 = 0; k0 < K; k0 += 32) {
    int ka = k0 + quad*8;
    bf16x8 ah[4], al[4], wh[4], wl[4];
    #pragma unroll
    for (int t=0;t<4;++t){
      ah[t] = *(const bf16x8*)(Abh + (long)(row0 + t*16 + l15)*K + ka);
      if (TERMS>=2) al[t] = *(const bf16x8*)(Abl + (long)(row0 + t*16 + l15)*K + ka);
      wh[t] = *(const bf16x8*)(Wbh + (long)(col0 + t*16 + l15)*K + ka);
      if (TERMS==3) wl[t] = *(const bf16x8*)(Wbl + (long)(col0 + t*16 + l15)*K + ka);
    }
    #pragma unroll
    for (int tm=0;tm<4;++tm){
      #pragma unroll
      for (int tn=0;tn<4;++tn){
        acc[tm][tn] = MFMA16(ah[tm], wh[tn], acc[tm][tn]);
        if (TERMS>=2) acc[tm][tn] = MFMA16(al[tm], wh[tn], acc[tm][tn]);
        if (TERMS==3) acc[tm][tn] = MFMA16(ah[tm], wl[tn], acc[tm][tn]);
      }
    }
  }
  #pragma unroll
  for (int tm=0;tm<4;++tm){
    #pragma unroll
    for (int tn=0;tn<4;++tn){
      #pragma unroll
      for (int r=0;r<4;++r){
        int row = row0 + tm*16 + quad*4 + r;
        int col = col0 + tn*16 + l15;
        float v = acc[tm][tn][r];
        if (BIAS==1) v += bias[col];
        else if (BIAS==2) v += bias[row];
        long idx = (long)row*N + col;
        unsigned short h = f2bs(v);
        Cbh[idx] = h;
        if (SOUT) Cbl[idx] = f2bs(v - bs2f(h));
      }
    }
  }
}

// ---------------- stage-1 attention (split precision, parallel softmax) ----------------
__global__ __launch_bounds__(256) void k_attn1(
    const unsigned short* __restrict__ qh, const unsigned short* __restrict__ ql,
    const unsigned short* __restrict__ kh, const unsigned short* __restrict__ kl,
    const unsigned short* __restrict__ vh, const unsigned short* __restrict__ vl,
    unsigned short* __restrict__ fh, unsigned short* __restrict__ fl)
{
  __shared__ float Sb[64][72];
  __shared__ __align__(16) unsigned short Ph[64][72];
  __shared__ __align__(16) unsigned short Pl[64][72];
  __shared__ float pred[4][64];
  __shared__ float rowm[64], rowinv[64];
  int bn = blockIdx.x, b = bn/12;
  int tid=threadIdx.x, wave=tid>>6, lane=tid&63, quad=lane>>4, l15=lane&15;
  const unsigned short* Qh = qh + (long)bn*64*256;
  const unsigned short* Ql = ql + (long)bn*64*256;
  const unsigned short* Kh = kh + (long)b *64*256;
  const unsigned short* Kl = kl + (long)b *64*256;
  f32x4 sacc[4] = {};
  #pragma unroll 2
  for (int k0=0;k0<256;k0+=32){
    int ka = k0 + quad*8;
    bf16x8 qfh = *(const bf16x8*)(Qh + (long)(16*wave + l15)*256 + ka);
    bf16x8 qfl = *(const bf16x8*)(Ql + (long)(16*wave + l15)*256 + ka);
    #pragma unroll
    for (int t=0;t<4;++t){
      bf16x8 kfh = *(const bf16x8*)(Kh + (long)(t*16 + l15)*256 + ka);
      bf16x8 kfl = *(const bf16x8*)(Kl + (long)(t*16 + l15)*256 + ka);
      sacc[t] = MFMA16(qfh, kfh, sacc[t]);
      sacc[t] = MFMA16(qfl, kfh, sacc[t]);
      sacc[t] = MFMA16(qfh, kfl, sacc[t]);
    }
  }
  #pragma unroll
  for (int t=0;t<4;++t)
    #pragma unroll
    for (int r=0;r<4;++r)
      Sb[16*wave + quad*4 + r][t*16 + l15] = sacc[t][r] * 0.0625f;
  __syncthreads();
  // parallel softmax: 4 col-slices per row
  {
    int r = tid & 63, part = tid >> 6;
    int c0 = part*16;
    int cend = (c0+16 > 49) ? 49 : c0+16;
    float m = -1e30f;
    for (int c=c0;c<cend;++c) m = fmaxf(m, Sb[r][c]);
    pred[part][r] = m;
    __syncthreads();
    if (part==0) rowm[r] = fmaxf(fmaxf(pred[0][r],pred[1][r]),fmaxf(pred[2][r],pred[3][r]));
    __syncthreads();
    float mm = rowm[r];
    float s = 0.f;
    for (int c=c0;c<cend;++c){ float e=__expf(Sb[r][c]-mm); s+=e; Sb[r][c]=e; }
    pred[part][r] = s;
    __syncthreads();
    if (part==0) rowinv[r] = 1.f/(pred[0][r]+pred[1][r]+pred[2][r]+pred[3][r]);
    __syncthreads();
    float inv = rowinv[r];
    #pragma unroll
    for (int cc=0;cc<16;++cc){
      int c = c0+cc;
      float pv = (c<49) ? Sb[r][c]*inv : 0.f;
      unsigned short h = f2bs(pv);
      Ph[r][c] = h;
      Pl[r][c] = f2bs(pv - bs2f(h));
    }
  }
  __syncthreads();
  const unsigned short* Vh = vh + (long)b*512*64;
  const unsigned short* Vl = vl + (long)b*512*64;
  unsigned short* Fh = fh + (long)bn*64*512;
  unsigned short* Fl = fl + (long)bn*64*512;
  for (int nc=0;nc<4;++nc){
    f32x4 acc[8] = {};
    #pragma unroll
    for (int kk=0;kk<2;++kk){
      int k0 = kk*32 + quad*8;
      bf16x8 pfh = *(const bf16x8*)(&Ph[16*wave + l15][k0]);
      bf16x8 pfl = *(const bf16x8*)(&Pl[16*wave + l15][k0]);
      #pragma unroll
      for (int t=0;t<8;++t){
        bf16x8 vfh = *(const bf16x8*)(Vh + (long)(nc*128 + t*16 + l15)*64 + k0);
        bf16x8 vfl = *(const bf16x8*)(Vl + (long)(nc*128 + t*16 + l15)*64 + k0);
        acc[t] = MFMA16(pfh, vfh, acc[t]);
        acc[t] = MFMA16(pfl, vfh, acc[t]);
        acc[t] = MFMA16(pfh, vfl, acc[t]);
      }
    }
    #pragma unroll
    for (int t=0;t<8;++t){
      #pragma unroll
      for (int r=0;r<4;++r){
        long idx = (long)(16*wave + quad*4 + r)*512 + nc*128 + t*16 + l15;
        float v = acc[t][r];
        unsigned short h = f2bs(v);
        Fh[idx] = h;
        Fl[idx] = f2bs(v - bs2f(h));
      }
    }
  }
}

// ---------------- Gram: G[b,i] = EV^T EV (64x64 fp32), evec[b,i][k] = sum_c EV[c,k] ----------------
__global__ __launch_bounds__(256) void k_gram(
    const unsigned short* __restrict__ EV,
    float* __restrict__ G, float* __restrict__ evec)
{
  __shared__ __align__(16) unsigned short Et[64][520];
  __shared__ float ered[4][64];
  int bn = blockIdx.x;
  int tid = threadIdx.x, wave = tid>>6, lane = tid&63, quad = lane>>4, l15 = lane&15;
  const unsigned short* E = EV + (long)bn*512*64;
  for (int rep=0; rep<16; ++rep){
    int idx = rep*256 + tid;
    int c = idx >> 3;
    int kg = idx & 7;
    bf16x8 v = *(const bf16x8*)(E + (long)c*64 + kg*8);
    #pragma unroll
    for (int j=0;j<8;++j) Et[kg*8+j][c] = (unsigned short)v[j];
  }
  __syncthreads();
  f32x4 acc[4] = {};
  #pragma unroll 2
  for (int ks=0; ks<16; ++ks){
    bf16x8 a = *(const bf16x8*)(&Et[wave*16 + l15][ks*32 + quad*8]);
    #pragma unroll
    for (int n=0;n<4;++n){
      bf16x8 bb = *(const bf16x8*)(&Et[n*16 + l15][ks*32 + quad*8]);
      acc[n] = MFMA16(a, bb, acc[n]);
    }
  }
  float* Gb = G + (long)bn*4096;
  #pragma unroll
  for (int n=0;n<4;++n)
    #pragma unroll
    for (int r=0;r<4;++r)
      Gb[(wave*16 + quad*4 + r)*64 + n*16 + l15] = acc[n][r];
  int k = tid & 63, part = tid >> 6;
  float s = 0.f;
  for (int c = part*128; c < part*128 + 128; ++c) s += bs2f(Et[k][c]);
  ered[part][k] = s;
  __syncthreads();
  if (tid < 64) evec[(long)bn*64 + tid] = ered[0][tid] + ered[1][tid] + ered[2][tid] + ered[3][tid];
}

// ---------------- stage-2 logits + parallel softmax -> P2, fused BN-stats (Gram trick) ----------------
__global__ __launch_bounds__(256) void k_attnA(
    const unsigned short* __restrict__ qh, const unsigned short* __restrict__ ql,
    const unsigned short* __restrict__ kh, const unsigned short* __restrict__ kl,
    unsigned short* __restrict__ P2,
    const float* __restrict__ G, const float* __restrict__ evec,
    float* __restrict__ stats)
{
  __shared__ float Sb[64][72];
  __shared__ __align__(16) unsigned short Pt[64][72];
  __shared__ float pred[4][64];
  __shared__ float rowm[64], rowinv[64];
  __shared__ float red[8];
  int p = blockIdx.x, b = blockIdx.y;
  int i = p/12, j = p%12;
  int tid=threadIdx.x, wave=tid>>6, lane=tid&63, quad=lane>>4, l15=lane&15;
  const unsigned short* Qh = qh + ((long)(b*12 + j))*64*256;
  const unsigned short* Ql = ql + ((long)(b*12 + j))*64*256;
  const unsigned short* Kh = kh + ((long)(b*12 + i))*64*256;
  const unsigned short* Kl = kl + ((long)(b*12 + i))*64*256;
  f32x4 sacc[4] = {};
  #pragma unroll 2
  for (int k0=0;k0<256;k0+=32){
    int ka = k0 + quad*8;
    bf16x8 qfh = *(const bf16x8*)(Qh + (long)(16*wave + l15)*256 + ka);
    bf16x8 qfl = *(const bf16x8*)(Ql + (long)(16*wave + l15)*256 + ka);
    #pragma unroll
    for (int t=0;t<4;++t){
      bf16x8 kfh = *(const bf16x8*)(Kh + (long)(t*16 + l15)*256 + ka);
      bf16x8 kfl = *(const bf16x8*)(Kl + (long)(t*16 + l15)*256 + ka);
      sacc[t] = MFMA16(qfh, kfh, sacc[t]);
      sacc[t] = MFMA16(qfl, kfh, sacc[t]);
      sacc[t] = MFMA16(qfh, kfl, sacc[t]);
    }
  }
  #pragma unroll
  for (int t=0;t<4;++t)
    #pragma unroll
    for (int r=0;r<4;++r)
      Sb[16*wave + quad*4 + r][t*16 + l15] = sacc[t][r] * 0.0625f;
  __syncthreads();
  int r = tid & 63, part = tid >> 6;
  int c0 = part*16;
  {
    int cend = (c0+16 > 49) ? 49 : c0+16;
    float m = -1e30f;
    for (int c=c0;c<cend;++c) m = fmaxf(m, Sb[r][c]);
    pred[part][r] = m;
    __syncthreads();
    if (part==0) rowm[r] = fmaxf(fmaxf(pred[0][r],pred[1][r]),fmaxf(pred[2][r],pred[3][r]));
    __syncthreads();
    float mm = rowm[r];
    float s = 0.f;
    for (int c=c0;c<cend;++c){ float e=__expf(Sb[r][c]-mm); s+=e; Sb[r][c]=e; }
    pred[part][r] = s;
    __syncthreads();
    if (part==0) rowinv[r] = 1.f/(pred[0][r]+pred[1][r]+pred[2][r]+pred[3][r]);
    __syncthreads();
    float inv = rowinv[r];
    unsigned short buf[16];
    #pragma unroll
    for (int cc=0;cc<16;++cc){
      int c = c0+cc;
      float pv = (r<49 && c<49) ? Sb[r][c]*inv : 0.f;
      unsigned short h = f2bs(pv);
      buf[cc] = h;
      Pt[c][r] = h;   // transpose: Pt[k][q]
    }
    __builtin_memcpy(P2 + ((long)(b*144 + p)*64 + r)*64 + c0, buf, 32);
  }
  __syncthreads();
  // P^T P (64x64x64) and dot with G
  const float* Gb = G + (long)(b*12 + i)*4096;
  f32x4 pac[4] = {};
  #pragma unroll
  for (int ks=0; ks<2; ++ks){
    bf16x8 a = *(const bf16x8*)(&Pt[wave*16 + l15][ks*32 + quad*8]);
    #pragma unroll
    for (int n=0;n<4;++n){
      bf16x8 bb = *(const bf16x8*)(&Pt[n*16 + l15][ks*32 + quad*8]);
      pac[n] = MFMA16(a, bb, pac[n]);
    }
  }
  float psq = 0.f;
  #pragma unroll
  for (int n=0;n<4;++n)
    #pragma unroll
    for (int rr=0;rr<4;++rr)
      psq += pac[n][rr] * Gb[(wave*16 + quad*4 + rr)*64 + n*16 + l15];
  #pragma unroll
  for (int off=32; off; off>>=1) psq += __shfl_xor(psq, off, 64);
  if (lane==0) red[4+wave] = psq;
  // psum partials: colsum of P = rowsum of Pt, parallel over 4 q-slices
  {
    float sp = 0.f;
    for (int q=c0;q<c0+16;++q) sp += bs2f(Pt[r][q]);
    pred[part][r] = sp;
  }
  __syncthreads();
  if (tid < 64){
    float sk = pred[0][tid]+pred[1][tid]+pred[2][tid]+pred[3][tid];
    float psm = sk * evec[(long)(b*12 + i)*64 + tid];
    #pragma unroll
    for (int off=32; off; off>>=1) psm += __shfl_xor(psm, off, 64);
    if (tid==0) red[0] = psm;
  }
  __syncthreads();
  if (tid == 0){
    atomicAdd(&stats[p],     red[0]);
    atomicAdd(&stats[144+p], red[4]+red[5]+red[6]+red[7]);
  }
}

// ---------------- stage-2 PV: recompute, normalize, write fp32 out ----------------
__global__ __launch_bounds__(256) void k_attnW(
    const unsigned short* __restrict__ P2, const unsigned short* __restrict__ EV,
    const float* __restrict__ stats,
    const float* __restrict__ bnw, const float* __restrict__ bnb,
    float* __restrict__ out)
{
  int p = blockIdx.x, b = blockIdx.y;
  int i = p/12;
  int tid=threadIdx.x, wave=tid>>6, lane=tid&63, quad=lane>>4, l15=lane&15;
  const unsigned short* Pz = P2 + (long)(b*144 + p)*64*64;
  const unsigned short* E  = EV + ((long)(b*12 + i))*512*64;
  const float invc = 1.f/401408.f;
  float mean = stats[p] * invc;
  float var  = stats[144+p] * invc - mean*mean;
  float g  = bnw[p] * rsqrtf(var + 1e-5f);
  float sh = bnb[p] - mean*g;
  for (int nc=0;nc<4;++nc){
    f32x4 acc[8] = {};
    #pragma unroll
    for (int kk=0;kk<2;++kk){
      int k0 = kk*32 + quad*8;
      bf16x8 pf = *(const bf16x8*)(Pz + (long)(16*wave + l15)*64 + k0);
      #pragma unroll
      for (int t=0;t<8;++t){
        bf16x8 ef = *(const bf16x8*)(E + (long)(nc*128 + t*16 + l15)*64 + k0);
        acc[t] = MFMA16(pf, ef, acc[t]);
      }
    }
    #pragma unroll
    for (int t=0;t<8;++t){
      #pragma unroll
      for (int r=0;r<4;++r){
        int q = 16*wave + quad*4 + r;
        if (q < 49)
          out[(((long)(b*144 + p))*49 + q)*512 + (nc*128 + t*16 + l15)] = acc[t][r]*g + sh;
      }
    }
  }
}

extern "C" void kernel_launch(void* const* d_in, const int* in_sizes, int n_in,
                              void* d_out, int out_size, void* d_ws, size_t ws_size,
                              hipStream_t stream)
{
  const float* cf  = (const float*)d_in[0];
  const float* gf  = (const float*)d_in[1];
  const float* fqw = (const float*)d_in[2];   const float* fqb = (const float*)d_in[3];
  const float* fkw = (const float*)d_in[4];   const float* fkb = (const float*)d_in[5];
  const float* fvw = (const float*)d_in[6];   const float* fvb = (const float*)d_in[7];
  const float* aqw = (const float*)d_in[8];   const float* aqb = (const float*)d_in[9];
  const float* akw = (const float*)d_in[10];  const float* akb = (const float*)d_in[11];
  const float* avw = (const float*)d_in[12];  const float* avb = (const float*)d_in[13];
  const float* ew  = (const float*)d_in[14];  const float* ebv = (const float*)d_in[15];
  const float* bnw = (const float*)d_in[16];  const float* bnb = (const float*)d_in[17];

  // ---- d_ws (~31.5 MB): stats | P2 (weights overlaid; dead before P2 written) | EV ----
  char* WS = (char*)d_ws;
  float* stats = (float*)WS;                                   // 288 fp32
  unsigned short* P2 = (unsigned short*)(WS + 4096);           // 16*144*64*64
  unsigned short* EV = (unsigned short*)(WS + 4096 + 18874368);// 192*512*64
  unsigned short* wp = P2;  // weights overlay (consumed before attnA writes P2)
  unsigned short* w_fqw_h = wp; wp += 131072;  unsigned short* w_fqw_l = wp; wp += 131072;
  unsigned short* w_fkw_h = wp; wp += 131072;  unsigned short* w_fkw_l = wp; wp += 131072;
  unsigned short* w_fvw_h = wp; wp += 262144;  unsigned short* w_fvw_l = wp; wp += 262144;
  unsigned short* w_aqw_h = wp; wp += 131072;  unsigned short* w_aqw_l = wp; wp += 131072;
  unsigned short* w_akw_h = wp; wp += 131072;  unsigned short* w_akw_l = wp; wp += 131072;
  unsigned short* w_avw_h = wp; wp += 262144;
  unsigned short* w_ew_h  = wp; wp += 262144;

  // ---- d_out (231 MB fp32) as bf16 scratch for intermediates dead before k_attnW ----
  unsigned short* S = (unsigned short*)d_out;
  unsigned short* cfh = S; S += 6291456;  unsigned short* cfl = S; S += 6291456;
  unsigned short* gfh = S; S += 524288;   unsigned short* gfl = S; S += 524288;
  unsigned short* q1h = S; S += 3145728;  unsigned short* q1l = S; S += 3145728;
  unsigned short* k1h = S; S += 262144;   unsigned short* k1l = S; S += 262144;
  unsigned short* v1h = S; S += 524288;   unsigned short* v1l = S; S += 524288;
  unsigned short* feh = S; S += 6291456;  unsigned short* fel = S; S += 6291456;
  unsigned short* q2h = S; S += 3145728;  unsigned short* q2l = S; S += 3145728;
  unsigned short* k2h = S; S += 3145728;  unsigned short* k2l = S; S += 3145728;
  unsigned short* v2  = S; S += 6291456;  // single bf16
  float* G    = (float*)S; S += 1572864;  // 192 * 64*64 fp32 Gram matrices
  float* evec = (float*)S; S += 24576;    // 192 * 64 fp32 column sums

  // pad both inputs + zero stats (1 launch)
  k_pad2<<<6656, 256, 0, stream>>>(cf, gf, cfh, cfl, gfh, gfl, stats);

  // all 7 weight splits (1 launch)
  SplitArgs sa;
  sa.src[0]=fqw; sa.hi[0]=w_fqw_h; sa.lo[0]=w_fqw_l; sa.n[0]=131072;
  sa.src[1]=fkw; sa.hi[1]=w_fkw_h; sa.lo[1]=w_fkw_l; sa.n[1]=131072;
  sa.src[2]=fvw; sa.hi[2]=w_fvw_h; sa.lo[2]=w_fvw_l; sa.n[2]=262144;
  sa.src[3]=aqw; sa.hi[3]=w_aqw_h; sa.lo[3]=w_aqw_l; sa.n[3]=131072;
  sa.src[4]=akw; sa.hi[4]=w_akw_h; sa.lo[4]=w_akw_l; sa.n[4]=131072;
  sa.src[5]=avw; sa.hi[5]=w_avw_h; sa.lo[5]=nullptr; sa.n[5]=262144;
  sa.src[6]=ew;  sa.hi[6]=w_ew_h;  sa.lo[6]=nullptr; sa.n[6]=262144;
  k_splitall<<<dim3(256,7), 256, 0, stream>>>(sa);

  // q1 = cfp @ fqw^T + fqb   (12288,256) split out
  k_gemm<3,1,true,1,4><<<dim3(192,1,1),256,0,stream>>>(cfh,cfl,0, w_fqw_h,w_fqw_l,0, fqb, q1h,q1l,0, 512,256);
  // k1 = gfp @ fkw^T + fkb   (1024,256)
  k_gemm<3,1,true,1,4><<<dim3(16,1,1),256,0,stream>>>(gfh,gfl,0, w_fkw_h,w_fkw_l,0, fkb, k1h,k1l,0, 512,256);
  // v1T[b] = fvw @ gfp[b]^T + fvb(row)   (16 x 512,64)
  k_gemm<3,2,true,4,1><<<dim3(2,1,16),256,0,stream>>>(w_fvw_h,w_fvw_l,0, gfh,gfl,(long)64*512, fvb, v1h,v1l,(long)512*64, 512,64);

  k_attn1<<<192,256,0,stream>>>(q1h,q1l,k1h,k1l,v1h,v1l,feh,fel);

  // Q2/K2 = fea @ a{q,k}w^T + b  (12288,256) split out
  k_gemm<3,1,true,1,4><<<dim3(192,1,1),256,0,stream>>>(feh,fel,0, w_aqw_h,w_aqw_l,0, aqb, q2h,q2l,0, 512,256);
  k_gemm<3,1,true,1,4><<<dim3(192,1,1),256,0,stream>>>(feh,fel,0, w_akw_h,w_akw_l,0, akb, k2h,k2l,0, 512,256);
  // V2 = fea @ avw^T + avb  (12288,512) single out, 2-term
  k_gemm<2,1,false,1,4><<<dim3(192,2,1),256,0,stream>>>(feh,fel,0, w_avw_h,nullptr,0, avb, v2,nullptr,0, 512,512);
  // EV[bn] = ew @ V2[bn]^T + edge_b(row)  (192 x 512,64) single
  k_gemm<1,2,false,4,1><<<dim3(2,1,192),256,0,stream>>>(w_ew_h,nullptr,0, v2,nullptr,(long)64*512, ebv, EV,nullptr,(long)512*64, 512,64);

  // Gram matrices of EV (replaces the full stats PV pass)
  k_gram<<<192,256,0,stream>>>(EV, G, evec);

  // softmax + P2 + fused BN stats
  k_attnA<<<dim3(144,16),256,0,stream>>>(q2h,q2l,k2h,k2l,P2,G,evec,stats);

  // PV + fused BN normalize, write fp32 out
  k_attnW<<<dim3(144,16),256,0,stream>>>(P2,EV,stats,bnw,bnb,(float*)d_out);
}

// Round 6
// 641.879 us; speedup vs baseline: 1.2530x; 1.1637x over previous
//
#include <hip/hip_runtime.h>
#include <hip/hip_bf16.h>

using bf16 = __hip_bfloat16;
using bf16x8 = __attribute__((ext_vector_type(8))) short;
using f32x4  = __attribute__((ext_vector_type(4))) float;

#define MFMA16(a,b,c) __builtin_amdgcn_mfma_f32_16x16x32_bf16(a,b,c,0,0,0)

static __device__ __forceinline__ unsigned short f2bs(float v){
  bf16 t = __float2bfloat16(v); unsigned short s; __builtin_memcpy(&s,&t,2); return s;
}
static __device__ __forceinline__ float bs2f(unsigned short s){
  bf16 t; __builtin_memcpy(&t,&s,2); return __bfloat162float(t);
}

// ---------------- job descriptor for merged GEMM launches ----------------
struct GJob {
  const unsigned short *Ah, *Al, *Wh, *Wl;
  const float* bias;
  unsigned short *Ch, *Cl;
  long a_bs, w_bs, c_bs;
  int K, N, nx;
};

// ---------------- merged prep: pad cf/gf + all weight splits + zero stats ----------------
struct SplitArgs {
  const float* src[7];
  unsigned short* hi[7];
  unsigned short* lo[7];
};

__global__ __launch_bounds__(256) void k_prep(const float* __restrict__ cf, const float* __restrict__ gf,
                                              unsigned short* __restrict__ cfh, unsigned short* __restrict__ cfl,
                                              unsigned short* __restrict__ gfh, unsigned short* __restrict__ gfl,
                                              float* __restrict__ stats, SplitArgs sa){
  int blk = blockIdx.x;
  if (blk == 0){
    stats[threadIdx.x] = 0.f;
    if (threadIdx.x < 32) stats[256 + threadIdx.x] = 0.f;
  }
  if (blk < 6656){
    // pad branch
    const float* src; unsigned short* dh; unsigned short* dl; long base;
    if (blk < 6144){ src = cf; dh = cfh; dl = cfl; base = (long)blk*1024; }
    else           { src = gf; dh = gfh; dl = gfl; base = (long)(blk-6144)*1024; }
    long e = base + (long)threadIdx.x*4;
    int rem = (int)(e % (64*512));
    int d = rem >> 9;
    unsigned short h[4], l[4];
    if (d < 49){
      int mat = (int)(e / (64*512));
      int c = rem & 511;
      const float* s = src + ((long)mat*49 + d)*512 + c;
      #pragma unroll
      for (int t=0;t<4;++t){
        float v = s[t];
        h[t] = f2bs(v);
        l[t] = f2bs(v - bs2f(h[t]));
      }
    } else {
      #pragma unroll
      for (int t=0;t<4;++t){ h[t]=0; l[t]=0; }
    }
    uint2 vh, vl; __builtin_memcpy(&vh,h,8); __builtin_memcpy(&vl,l,8);
    *(uint2*)(dh + e) = vh;
    *(uint2*)(dl + e) = vl;
  } else {
    // split branch: job block counts {128,128,256,128,128,256,256}
    int l = blk - 6656;
    int j, base;
    if      (l < 128) { j=0; base=0;    }
    else if (l < 256) { j=1; base=128;  }
    else if (l < 512) { j=2; base=256;  }
    else if (l < 640) { j=3; base=512;  }
    else if (l < 768) { j=4; base=640;  }
    else if (l <1024) { j=5; base=768;  }
    else              { j=6; base=1024; }
    long e = ((long)(l-base)*256 + threadIdx.x)*4;
    const float* src = sa.src[j];
    unsigned short* hi = sa.hi[j];
    unsigned short* lo = sa.lo[j];
    unsigned short h[4], lw[4];
    #pragma unroll
    for (int t=0;t<4;++t){
      float v = src[e+t];
      h[t] = f2bs(v);
      lw[t] = f2bs(v - bs2f(h[t]));
    }
    uint2 vh; __builtin_memcpy(&vh,h,8);
    *(uint2*)(hi + e) = vh;
    if (lo){ uint2 vl; __builtin_memcpy(&vl,lw,8); *(uint2*)(lo + e) = vl; }
  }
}

// ---------------- GEMM body (merged launches): C = A @ W^T + bias ----------------
template<int TERMS, int BIAS, bool SOUT, int WM, int WN>
static __device__ __forceinline__ void gemm_body(const GJob& jb, int bx, int by, int bz){
  const int K = jb.K, N = jb.N;
  const unsigned short* Abh = jb.Ah + (long)bz*jb.a_bs;
  const unsigned short* Abl = (TERMS>=2) ? jb.Al + (long)bz*jb.a_bs : nullptr;
  const unsigned short* Wbh = jb.Wh + (long)bz*jb.w_bs;
  const unsigned short* Wbl = (TERMS==3) ? jb.Wl + (long)bz*jb.w_bs : nullptr;
  unsigned short* Cbh = jb.Ch + (long)bz*jb.c_bs;
  unsigned short* Cbl = SOUT ? jb.Cl + (long)bz*jb.c_bs : nullptr;
  int tid = threadIdx.x, wave = tid>>6, lane = tid&63, quad = lane>>4, l15 = lane&15;
  int wm = (WN==1) ? wave : wave / WN;
  int wn = (WN==1) ? 0    : wave % WN;
  int row0 = bx*(64*WM) + wm*64;
  int col0 = by*(64*WN) + wn*64;
  f32x4 acc[4][4] = {};
  #pragma unroll 2
  for (int k0 = 0; k0 < K; k0 += 32) {
    int ka = k0 + quad*8;
    bf16x8 ah[4], al[4], wh[4], wl[4];
    #pragma unroll
    for (int t=0;t<4;++t){
      ah[t] = *(const bf16x8*)(Abh + (long)(row0 + t*16 + l15)*K + ka);
      if (TERMS>=2) al[t] = *(const bf16x8*)(Abl + (long)(row0 + t*16 + l15)*K + ka);
      wh[t] = *(const bf16x8*)(Wbh + (long)(col0 + t*16 + l15)*K + ka);
      if (TERMS==3) wl[t] = *(const bf16x8*)(Wbl + (long)(col0 + t*16 + l15)*K + ka);
    }
    #pragma unroll
    for (int tm=0;tm<4;++tm){
      #pragma unroll
      for (int tn=0;tn<4;++tn){
        acc[tm][tn] = MFMA16(ah[tm], wh[tn], acc[tm][tn]);
        if (TERMS>=2) acc[tm][tn] = MFMA16(al[tm], wh[tn], acc[tm][tn]);
        if (TERMS==3) acc[tm][tn] = MFMA16(ah[tm], wl[tn], acc[tm][tn]);
      }
    }
  }
  #pragma unroll
  for (int tm=0;tm<4;++tm){
    #pragma unroll
    for (int tn=0;tn<4;++tn){
      #pragma unroll
      for (int r=0;r<4;++r){
        int row = row0 + tm*16 + quad*4 + r;
        int col = col0 + tn*16 + l15;
        float v = acc[tm][tn][r];
        if (BIAS==1) v += jb.bias[col];
        else if (BIAS==2) v += jb.bias[row];
        long idx = (long)row*N + col;
        unsigned short h = f2bs(v);
        Cbh[idx] = h;
        if (SOUT) Cbl[idx] = f2bs(v - bs2f(h));
      }
    }
  }
}

// ---------------- standalone GEMM kernel (round-3 form, used for EV) ----------------
template<int TERMS, int BIAS, bool SOUT, int WM, int WN>
__global__ __launch_bounds__(256) void k_gemm(
    const unsigned short* __restrict__ Ah, const unsigned short* __restrict__ Al, long a_bs,
    const unsigned short* __restrict__ Wh, const unsigned short* __restrict__ Wl, long w_bs,
    const float* __restrict__ bias,
    unsigned short* __restrict__ Ch, unsigned short* __restrict__ Cl, long c_bs,
    int K, int N)
{
  GJob jb = {Ah,Al,Wh,Wl, bias, Ch,Cl, a_bs,w_bs,c_bs, K,N, 0};
  gemm_body<TERMS,BIAS,SOUT,WM,WN>(jb, blockIdx.x, blockIdx.y, blockIdx.z);
}

// ---------------- stage-B merged GEMMs: q1(192) | k1(16) | v1(32) ----------------
__global__ __launch_bounds__(256) void k_gemmB(GJob jq, GJob jk, GJob jv){
  int l = blockIdx.x;
  if (l < 192)      gemm_body<3,1,true,1,4>(jq, l, 0, 0);
  else if (l < 208) gemm_body<3,1,true,1,4>(jk, l-192, 0, 0);
  else {
    int l2 = l - 208;
    gemm_body<3,2,true,4,1>(jv, l2 & 1, 0, l2 >> 1);
  }
}

// ---------------- stage-D merged GEMMs: q2(192) | k2(192) | v2(384) ----------------
__global__ __launch_bounds__(256) void k_gemmD(GJob jq, GJob jk, GJob jv){
  int l = blockIdx.x;
  if (l < 192)      gemm_body<3,1,true,1,4>(jq, l, 0, 0);
  else if (l < 384) gemm_body<3,1,true,1,4>(jk, l-192, 0, 0);
  else {
    int l2 = l - 384;
    gemm_body<2,1,false,1,4>(jv, l2 % 192, l2 / 192, 0);
  }
}

// ---------------- stage-1 attention (round-3, passing) ----------------
__global__ __launch_bounds__(256) void k_attn1(
    const unsigned short* __restrict__ qh, const unsigned short* __restrict__ ql,
    const unsigned short* __restrict__ kh, const unsigned short* __restrict__ kl,
    const unsigned short* __restrict__ vh, const unsigned short* __restrict__ vl,
    unsigned short* __restrict__ fh, unsigned short* __restrict__ fl)
{
  __shared__ float Sb[64][72];
  __shared__ __align__(16) unsigned short Ph[64][72];
  __shared__ __align__(16) unsigned short Pl[64][72];
  __shared__ float pred[4][64];
  __shared__ float rowm[64], rowinv[64];
  int bn = blockIdx.x, b = bn/12;
  int tid=threadIdx.x, wave=tid>>6, lane=tid&63, quad=lane>>4, l15=lane&15;
  const unsigned short* Qh = qh + (long)bn*64*256;
  const unsigned short* Ql = ql + (long)bn*64*256;
  const unsigned short* Kh = kh + (long)b *64*256;
  const unsigned short* Kl = kl + (long)b *64*256;
  f32x4 sacc[4] = {};
  #pragma unroll 2
  for (int k0=0;k0<256;k0+=32){
    int ka = k0 + quad*8;
    bf16x8 qfh = *(const bf16x8*)(Qh + (long)(16*wave + l15)*256 + ka);
    bf16x8 qfl = *(const bf16x8*)(Ql + (long)(16*wave + l15)*256 + ka);
    #pragma unroll
    for (int t=0;t<4;++t){
      bf16x8 kfh = *(const bf16x8*)(Kh + (long)(t*16 + l15)*256 + ka);
      bf16x8 kfl = *(const bf16x8*)(Kl + (long)(t*16 + l15)*256 + ka);
      sacc[t] = MFMA16(qfh, kfh, sacc[t]);
      sacc[t] = MFMA16(qfl, kfh, sacc[t]);
      sacc[t] = MFMA16(qfh, kfl, sacc[t]);
    }
  }
  #pragma unroll
  for (int t=0;t<4;++t)
    #pragma unroll
    for (int r=0;r<4;++r)
      Sb[16*wave + quad*4 + r][t*16 + l15] = sacc[t][r] * 0.0625f;
  __syncthreads();
  {
    int r = tid & 63, part = tid >> 6;
    int c0 = part*16;
    int cend = (c0+16 > 49) ? 49 : c0+16;
    float m = -1e30f;
    for (int c=c0;c<cend;++c) m = fmaxf(m, Sb[r][c]);
    pred[part][r] = m;
    __syncthreads();
    if (part==0) rowm[r] = fmaxf(fmaxf(pred[0][r],pred[1][r]),fmaxf(pred[2][r],pred[3][r]));
    __syncthreads();
    float mm = rowm[r];
    float s = 0.f;
    for (int c=c0;c<cend;++c){ float e=__expf(Sb[r][c]-mm); s+=e; Sb[r][c]=e; }
    pred[part][r] = s;
    __syncthreads();
    if (part==0) rowinv[r] = 1.f/(pred[0][r]+pred[1][r]+pred[2][r]+pred[3][r]);
    __syncthreads();
    float inv = rowinv[r];
    #pragma unroll
    for (int cc=0;cc<16;++cc){
      int c = c0+cc;
      float pv = (c<49) ? Sb[r][c]*inv : 0.f;
      unsigned short h = f2bs(pv);
      Ph[r][c] = h;
      Pl[r][c] = f2bs(pv - bs2f(h));
    }
  }
  __syncthreads();
  const unsigned short* Vh = vh + (long)b*512*64;
  const unsigned short* Vl = vl + (long)b*512*64;
  unsigned short* Fh = fh + (long)bn*64*512;
  unsigned short* Fl = fl + (long)bn*64*512;
  for (int nc=0;nc<4;++nc){
    f32x4 acc[8] = {};
    #pragma unroll
    for (int kk=0;kk<2;++kk){
      int k0 = kk*32 + quad*8;
      bf16x8 pfh = *(const bf16x8*)(&Ph[16*wave + l15][k0]);
      bf16x8 pfl = *(const bf16x8*)(&Pl[16*wave + l15][k0]);
      #pragma unroll
      for (int t=0;t<8;++t){
        bf16x8 vfh = *(const bf16x8*)(Vh + (long)(nc*128 + t*16 + l15)*64 + k0);
        bf16x8 vfl = *(const bf16x8*)(Vl + (long)(nc*128 + t*16 + l15)*64 + k0);
        acc[t] = MFMA16(pfh, vfh, acc[t]);
        acc[t] = MFMA16(pfl, vfh, acc[t]);
        acc[t] = MFMA16(pfh, vfl, acc[t]);
      }
    }
    #pragma unroll
    for (int t=0;t<8;++t){
      #pragma unroll
      for (int r=0;r<4;++r){
        long idx = (long)(16*wave + quad*4 + r)*512 + nc*128 + t*16 + l15;
        float v = acc[t][r];
        unsigned short h = f2bs(v);
        Fh[idx] = h;
        Fl[idx] = f2bs(v - bs2f(h));
      }
    }
  }
}

// ---------------- Gram (round-3, passing): G = EV^T EV, evec = colsum EV ----------------
__global__ __launch_bounds__(256) void k_gram(
    const unsigned short* __restrict__ EV,
    float* __restrict__ G, float* __restrict__ evec)
{
  __shared__ __align__(16) unsigned short Et[64][520];
  __shared__ float ered[4][64];
  int bn = blockIdx.x;
  int tid = threadIdx.x, wave = tid>>6, lane = tid&63, quad = lane>>4, l15 = lane&15;
  const unsigned short* E = EV + (long)bn*512*64;
  for (int rep=0; rep<16; ++rep){
    int idx = rep*256 + tid;
    int c = idx >> 3;
    int kg = idx & 7;
    bf16x8 v = *(const bf16x8*)(E + (long)c*64 + kg*8);
    #pragma unroll
    for (int j=0;j<8;++j) Et[kg*8+j][c] = (unsigned short)v[j];
  }
  __syncthreads();
  f32x4 acc[4] = {};
  #pragma unroll 2
  for (int ks=0; ks<16; ++ks){
    bf16x8 a = *(const bf16x8*)(&Et[wave*16 + l15][ks*32 + quad*8]);
    #pragma unroll
    for (int n=0;n<4;++n){
      bf16x8 bb = *(const bf16x8*)(&Et[n*16 + l15][ks*32 + quad*8]);
      acc[n] = MFMA16(a, bb, acc[n]);
    }
  }
  float* Gb = G + (long)bn*4096;
  #pragma unroll
  for (int n=0;n<4;++n)
    #pragma unroll
    for (int r=0;r<4;++r)
      Gb[(wave*16 + quad*4 + r)*64 + n*16 + l15] = acc[n][r];
  int k = tid & 63, part = tid >> 6;
  float s = 0.f;
  for (int c = part*128; c < part*128 + 128; ++c) s += bs2f(Et[k][c]);
  ered[part][k] = s;
  __syncthreads();
  if (tid < 64) evec[(long)bn*64 + tid] = ered[0][tid] + ered[1][tid] + ered[2][tid] + ered[3][tid];
}

// ---------------- stage-2 logits + parallel softmax -> P2, fused BN-stats (round-3, passing) ----------------
__global__ __launch_bounds__(256) void k_attnA(
    const unsigned short* __restrict__ qh, const unsigned short* __restrict__ ql,
    const unsigned short* __restrict__ kh, const unsigned short* __restrict__ kl,
    unsigned short* __restrict__ P2,
    const float* __restrict__ G, const float* __restrict__ evec,
    float* __restrict__ stats)
{
  __shared__ float Sb[64][72];
  __shared__ __align__(16) unsigned short Pt[64][72];
  __shared__ float pred[4][64];
  __shared__ float rowm[64], rowinv[64];
  __shared__ float red[8];
  int p = blockIdx.x, b = blockIdx.y;
  int i = p/12, j = p%12;
  int tid=threadIdx.x, wave=tid>>6, lane=tid&63, quad=lane>>4, l15=lane&15;
  const unsigned short* Qh = qh + ((long)(b*12 + j))*64*256;
  const unsigned short* Ql = ql + ((long)(b*12 + j))*64*256;
  const unsigned short* Kh = kh + ((long)(b*12 + i))*64*256;
  const unsigned short* Kl = kl + ((long)(b*12 + i))*64*256;
  f32x4 sacc[4] = {};
  #pragma unroll 2
  for (int k0=0;k0<256;k0+=32){
    int ka = k0 + quad*8;
    bf16x8 qfh = *(const bf16x8*)(Qh + (long)(16*wave + l15)*256 + ka);
    bf16x8 qfl = *(const bf16x8*)(Ql + (long)(16*wave + l15)*256 + ka);
    #pragma unroll
    for (int t=0;t<4;++t){
      bf16x8 kfh = *(const bf16x8*)(Kh + (long)(t*16 + l15)*256 + ka);
      bf16x8 kfl = *(const bf16x8*)(Kl + (long)(t*16 + l15)*256 + ka);
      sacc[t] = MFMA16(qfh, kfh, sacc[t]);
      sacc[t] = MFMA16(qfl, kfh, sacc[t]);
      sacc[t] = MFMA16(qfh, kfl, sacc[t]);
    }
  }
  #pragma unroll
  for (int t=0;t<4;++t)
    #pragma unroll
    for (int r=0;r<4;++r)
      Sb[16*wave + quad*4 + r][t*16 + l15] = sacc[t][r] * 0.0625f;
  __syncthreads();
  int r = tid & 63, part = tid >> 6;
  int c0 = part*16;
  {
    int cend = (c0+16 > 49) ? 49 : c0+16;
    float m = -1e30f;
    for (int c=c0;c<cend;++c) m = fmaxf(m, Sb[r][c]);
    pred[part][r] = m;
    __syncthreads();
    if (part==0) rowm[r] = fmaxf(fmaxf(pred[0][r],pred[1][r]),fmaxf(pred[2][r],pred[3][r]));
    __syncthreads();
    float mm = rowm[r];
    float s = 0.f;
    for (int c=c0;c<cend;++c){ float e=__expf(Sb[r][c]-mm); s+=e; Sb[r][c]=e; }
    pred[part][r] = s;
    __syncthreads();
    if (part==0) rowinv[r] = 1.f/(pred[0][r]+pred[1][r]+pred[2][r]+pred[3][r]);
    __syncthreads();
    float inv = rowinv[r];
    unsigned short buf[16];
    #pragma unroll
    for (int cc=0;cc<16;++cc){
      int c = c0+cc;
      float pv = (r<49 && c<49) ? Sb[r][c]*inv : 0.f;
      unsigned short h = f2bs(pv);
      buf[cc] = h;
      Pt[c][r] = h;   // transpose: Pt[k][q]
    }
    __builtin_memcpy(P2 + ((long)(b*144 + p)*64 + r)*64 + c0, buf, 32);
  }
  __syncthreads();
  // P^T P (64x64x64) and dot with G
  const float* Gb = G + (long)(b*12 + i)*4096;
  f32x4 pac[4] = {};
  #pragma unroll
  for (int ks=0; ks<2; ++ks){
    bf16x8 a = *(const bf16x8*)(&Pt[wave*16 + l15][ks*32 + quad*8]);
    #pragma unroll
    for (int n=0;n<4;++n){
      bf16x8 bb = *(const bf16x8*)(&Pt[n*16 + l15][ks*32 + quad*8]);
      pac[n] = MFMA16(a, bb, pac[n]);
    }
  }
  float psq = 0.f;
  #pragma unroll
  for (int n=0;n<4;++n)
    #pragma unroll
    for (int rr=0;rr<4;++rr)
      psq += pac[n][rr] * Gb[(wave*16 + quad*4 + rr)*64 + n*16 + l15];
  #pragma unroll
  for (int off=32; off; off>>=1) psq += __shfl_xor(psq, off, 64);
  if (lane==0) red[4+wave] = psq;
  // psum partials: colsum of P = rowsum of Pt, parallel over 4 q-slices
  {
    float sp = 0.f;
    for (int q=c0;q<c0+16;++q) sp += bs2f(Pt[r][q]);
    pred[part][r] = sp;
  }
  __syncthreads();
  if (tid < 64){
    float sk = pred[0][tid]+pred[1][tid]+pred[2][tid]+pred[3][tid];
    float psm = sk * evec[(long)(b*12 + i)*64 + tid];
    #pragma unroll
    for (int off=32; off; off>>=1) psm += __shfl_xor(psm, off, 64);
    if (tid==0) red[0] = psm;
  }
  __syncthreads();
  if (tid == 0){
    atomicAdd(&stats[p],     red[0]);
    atomicAdd(&stats[144+p], red[4]+red[5]+red[6]+red[7]);
  }
}

// ---------------- stage-2 PV: recompute, normalize, write fp32 out (round-3, passing) ----------------
__global__ __launch_bounds__(256) void k_attnW(
    const unsigned short* __restrict__ P2, const unsigned short* __restrict__ EV,
    const float* __restrict__ stats,
    const float* __restrict__ bnw, const float* __restrict__ bnb,
    float* __restrict__ out)
{
  int p = blockIdx.x, b = blockIdx.y;
  int i = p/12;
  int tid=threadIdx.x, wave=tid>>6, lane=tid&63, quad=lane>>4, l15=lane&15;
  const unsigned short* Pz = P2 + (long)(b*144 + p)*64*64;
  const unsigned short* E  = EV + ((long)(b*12 + i))*512*64;
  const float invc = 1.f/401408.f;
  float mean = stats[p] * invc;
  float var  = stats[144+p] * invc - mean*mean;
  float g  = bnw[p] * rsqrtf(var + 1e-5f);
  float sh = bnb[p] - mean*g;
  for (int nc=0;nc<4;++nc){
    f32x4 acc[8] = {};
    #pragma unroll
    for (int kk=0;kk<2;++kk){
      int k0 = kk*32 + quad*8;
      bf16x8 pf = *(const bf16x8*)(Pz + (long)(16*wave + l15)*64 + k0);
      #pragma unroll
      for (int t=0;t<8;++t){
        bf16x8 ef = *(const bf16x8*)(E + (long)(nc*128 + t*16 + l15)*64 + k0);
        acc[t] = MFMA16(pf, ef, acc[t]);
      }
    }
    #pragma unroll
    for (int t=0;t<8;++t){
      #pragma unroll
      for (int r=0;r<4;++r){
        int q = 16*wave + quad*4 + r;
        if (q < 49)
          out[(((long)(b*144 + p))*49 + q)*512 + (nc*128 + t*16 + l15)] = acc[t][r]*g + sh;
      }
    }
  }
}

extern "C" void kernel_launch(void* const* d_in, const int* in_sizes, int n_in,
                              void* d_out, int out_size, void* d_ws, size_t ws_size,
                              hipStream_t stream)
{
  const float* cf  = (const float*)d_in[0];
  const float* gf  = (const float*)d_in[1];
  const float* fqw = (const float*)d_in[2];   const float* fqb = (const float*)d_in[3];
  const float* fkw = (const float*)d_in[4];   const float* fkb = (const float*)d_in[5];
  const float* fvw = (const float*)d_in[6];   const float* fvb = (const float*)d_in[7];
  const float* aqw = (const float*)d_in[8];   const float* aqb = (const float*)d_in[9];
  const float* akw = (const float*)d_in[10];  const float* akb = (const float*)d_in[11];
  const float* avw = (const float*)d_in[12];  const float* avb = (const float*)d_in[13];
  const float* ew  = (const float*)d_in[14];  const float* ebv = (const float*)d_in[15];
  const float* bnw = (const float*)d_in[16];  const float* bnb = (const float*)d_in[17];

  // ---- d_ws: stats | P2 | EV (no overlays) ----
  char* WS = (char*)d_ws;
  float* stats = (float*)WS;                                   // 288 fp32
  unsigned short* P2 = (unsigned short*)(WS + 4096);           // 16*144*64*64
  unsigned short* EV = (unsigned short*)(WS + 4096 + 18874368);// 192*512*64

  // ---- d_out (231 MB fp32) as bf16 scratch; ALL dead before k_attnW writes out ----
  unsigned short* S = (unsigned short*)d_out;
  unsigned short* cfh = S; S += 6291456;  unsigned short* cfl = S; S += 6291456;
  unsigned short* gfh = S; S += 524288;   unsigned short* gfl = S; S += 524288;
  unsigned short* q1h = S; S += 3145728;  unsigned short* q1l = S; S += 3145728;
  unsigned short* k1h = S; S += 262144;   unsigned short* k1l = S; S += 262144;
  unsigned short* v1h = S; S += 524288;   unsigned short* v1l = S; S += 524288;
  unsigned short* feh = S; S += 6291456;  unsigned short* fel = S; S += 6291456;
  unsigned short* q2h = S; S += 3145728;  unsigned short* q2l = S; S += 3145728;
  unsigned short* k2h = S; S += 3145728;  unsigned short* k2l = S; S += 3145728;
  unsigned short* v2  = S; S += 6291456;  // single bf16
  unsigned short* w_fqw_h = S; S += 131072;  unsigned short* w_fqw_l = S; S += 131072;
  unsigned short* w_fkw_h = S; S += 131072;  unsigned short* w_fkw_l = S; S += 131072;
  unsigned short* w_fvw_h = S; S += 262144;  unsigned short* w_fvw_l = S; S += 262144;
  unsigned short* w_aqw_h = S; S += 131072;  unsigned short* w_aqw_l = S; S += 131072;
  unsigned short* w_akw_h = S; S += 131072;  unsigned short* w_akw_l = S; S += 131072;
  unsigned short* w_avw_h = S; S += 262144;
  unsigned short* w_ew_h  = S; S += 262144;
  float* G    = (float*)S; S += 1572864;  // 192 * 64*64 fp32 Gram matrices
  float* evec = (float*)S; S += 24576;    // 192 * 64 fp32 column sums

  // 1) prep: pad cf/gf + all weight splits + zero stats
  SplitArgs sa;
  sa.src[0]=fqw; sa.hi[0]=w_fqw_h; sa.lo[0]=w_fqw_l;
  sa.src[1]=fkw; sa.hi[1]=w_fkw_h; sa.lo[1]=w_fkw_l;
  sa.src[2]=fvw; sa.hi[2]=w_fvw_h; sa.lo[2]=w_fvw_l;
  sa.src[3]=aqw; sa.hi[3]=w_aqw_h; sa.lo[3]=w_aqw_l;
  sa.src[4]=akw; sa.hi[4]=w_akw_h; sa.lo[4]=w_akw_l;
  sa.src[5]=avw; sa.hi[5]=w_avw_h; sa.lo[5]=nullptr;
  sa.src[6]=ew;  sa.hi[6]=w_ew_h;  sa.lo[6]=nullptr;
  k_prep<<<7936, 256, 0, stream>>>(cf, gf, cfh, cfl, gfh, gfl, stats, sa);

  // 2) stage-B GEMMs: q1 | k1 | v1
  GJob jq1 = {cfh,cfl,w_fqw_h,w_fqw_l, fqb, q1h,q1l, 0,0,0, 512,256, 0};
  GJob jk1 = {gfh,gfl,w_fkw_h,w_fkw_l, fkb, k1h,k1l, 0,0,0, 512,256, 0};
  GJob jv1 = {w_fvw_h,w_fvw_l,gfh,gfl, fvb, v1h,v1l, 0,(long)64*512,(long)512*64, 512,64, 0};
  k_gemmB<<<240, 256, 0, stream>>>(jq1, jk1, jv1);

  // 3) stage-1 attention
  k_attn1<<<192,256,0,stream>>>(q1h,q1l,k1h,k1l,v1h,v1l,feh,fel);

  // 4) stage-D GEMMs: q2 | k2 | v2
  GJob jq2 = {feh,fel,w_aqw_h,w_aqw_l, aqb, q2h,q2l, 0,0,0, 512,256, 0};
  GJob jk2 = {feh,fel,w_akw_h,w_akw_l, akb, k2h,k2l, 0,0,0, 512,256, 0};
  GJob jv2 = {feh,fel,w_avw_h,nullptr, avb, v2,nullptr, 0,0,0, 512,512, 0};
  k_gemmD<<<768, 256, 0, stream>>>(jq2, jk2, jv2);

  // 5) EV GEMM (standalone, round-3 form)
  k_gemm<1,2,false,4,1><<<dim3(2,1,192),256,0,stream>>>(w_ew_h,nullptr,0, v2,nullptr,(long)64*512, ebv, EV,nullptr,(long)512*64, 512,64);

  // 6) Gram matrices of EV
  k_gram<<<192,256,0,stream>>>(EV, G, evec);

  // 7) softmax + P2 + fused BN stats
  k_attnA<<<dim3(144,16),256,0,stream>>>(q2h,q2l,k2h,k2l,P2,G,evec,stats);

  // 8) PV + fused BN normalize, write fp32 out
  k_attnW<<<dim3(144,16),256,0,stream>>>(P2,EV,stats,bnw,bnb,(float*)d_out);
}